// Round 12
// baseline (140.228 us; speedup 1.0000x reference)
//
#include <hip/hip_runtime.h>
#include <hip/hip_bf16.h>

#define C_   32
#define K_   16
#define DLLM 768
#define DM   256
#define H_   8
#define DK   32
#define G_   256
#define BL   4096
#define NN   4096
#define E_   768
#define LDP  4160          // P / VWt row stride: 4096 + 32 bias-fold + 32 zero pad
#define TEMPF 0.17677669529663687f
#define SCL2  0.2550348647f   // TEMP * log2(e)

typedef __attribute__((ext_vector_type(8))) short bf16x8;
typedef __attribute__((ext_vector_type(4))) float f32x4;
typedef unsigned int u32;

__device__ __forceinline__ unsigned short f2bf(float f) {
    unsigned int u = __float_as_uint(f);
    unsigned int r = (u + 0x7fffu + ((u >> 16) & 1u)) >> 16;
    return (unsigned short)r;
}

// async global -> LDS, 16 bytes per lane (wave-uniform LDS base + lane*16)
__device__ __forceinline__ void gl16(const void* g, void* l) {
    __builtin_amdgcn_global_load_lds(
        (const __attribute__((address_space(1))) u32*)g,
        (__attribute__((address_space(3))) u32*)l, 16, 0, 0);
}

// ---------------------------------------------------------------- K1: kk/vv projections, coalesced wave-per-row
__global__ __launch_bounds__(256) void k1_kv(const float* __restrict__ topk,
                                             const float* __restrict__ kp,
                                             const float* __restrict__ vp,
                                             float* __restrict__ kk,
                                             float* __restrict__ vv) {
    const int c  = blockIdx.x;          // 0..31
    const int gq = blockIdx.y;          // 0..15
    const int t = threadIdx.x;
    const int lane = t & 63, w = t >> 6;

    __shared__ float t_l[K_][DLLM];     // 48 KB
    {
        const float4* src = reinterpret_cast<const float4*>(topk + (size_t)c * K_ * DLLM);
        float4* dst = reinterpret_cast<float4*>(&t_l[0][0]);
#pragma unroll
        for (int i = 0; i < 12; ++i)
            dst[t + i * 256] = src[t + i * 256];
    }
    __syncthreads();

#pragma unroll
    for (int gi = 0; gi < 4; ++gi) {
        const int g = gq * 16 + w * 4 + gi;
        const float* kpr = kp + (size_t)(c * G_ + g) * (DLLM + 1);
        const float* vpr = vp + (size_t)(c * G_ + g) * (DLLM + 1);
        const float bk = kpr[DLLM], bv = vpr[DLLM];
        float acck[K_] = {}, accv[K_] = {};
#pragma unroll
        for (int r = 0; r < 3; ++r) {
            const int d = r * 256 + lane * 4;
            float4 wk = *reinterpret_cast<const float4*>(kpr + d);
            float4 wv = *reinterpret_cast<const float4*>(vpr + d);
#pragma unroll
            for (int k = 0; k < K_; ++k) {
                float4 t4 = *reinterpret_cast<const float4*>(&t_l[k][d]);
                acck[k] += wk.x * t4.x + wk.y * t4.y + wk.z * t4.z + wk.w * t4.w;
                accv[k] += wv.x * t4.x + wv.y * t4.y + wv.z * t4.z + wv.w * t4.w;
            }
        }
#pragma unroll
        for (int s = 32; s >= 1; s >>= 1) {
#pragma unroll
            for (int k = 0; k < K_; ++k) {
                acck[k] += __shfl_xor(acck[k], s);
                accv[k] += __shfl_xor(accv[k], s);
            }
        }
        if (lane == 0) {
#pragma unroll
            for (int k = 0; k < K_; ++k) {
                kk[(size_t)(c * K_ + k) * G_ + g] = acck[k] + bk;
                vv[(size_t)(c * K_ + k) * G_ + g] = accv[k] + bv;
            }
        }
    }
}

// ---------------------------------------------------------------- k0: ts->bf16 + bias-fold/zero-pad cols + out zeroing
__global__ __launch_bounds__(256) void k0_cvt(const float* __restrict__ ts,
                                              const float* __restrict__ probs,
                                              const float* __restrict__ outb,
                                              unsigned short* __restrict__ tsb,
                                              unsigned short* __restrict__ P,
                                              unsigned short* __restrict__ VWt,
                                              float* __restrict__ out) {
    const int bid = blockIdx.x, t = threadIdx.x;
    if (bid < 1024) {                              // ts (4096x256) -> bf16
        const int idx = bid * 1024 + t * 4;
        float4 v = *reinterpret_cast<const float4*>(ts + idx);
        uint2 o;
        o.x = f2bf(v.x) | ((unsigned)f2bf(v.y) << 16);
        o.y = f2bf(v.z) | ((unsigned)f2bf(v.w) << 16);
        *reinterpret_cast<uint2*>(tsb + idx) = o;
    } else if (bid < 1056) {                       // P[:,4096+c]=probs, P[:,4128..4159]=0
        const int b2 = bid - 1024;
        const int row = b2 * 128 + (t >> 1);
        const int ch = (t & 1) * 16;
        unsigned short o[16];
#pragma unroll
        for (int j = 0; j < 16; ++j) o[j] = f2bf(probs[row * 32 + ch + j]);
        uint4 u0, u1;
        u0.x = o[0] | (o[1] << 16);  u0.y = o[2] | (o[3] << 16);
        u0.z = o[4] | (o[5] << 16);  u0.w = o[6] | (o[7] << 16);
        u1.x = o[8] | (o[9] << 16);  u1.y = o[10] | (o[11] << 16);
        u1.z = o[12] | (o[13] << 16); u1.w = o[14] | (o[15] << 16);
        unsigned short* dst = P + (size_t)row * LDP + 4096 + ch;
        *reinterpret_cast<uint4*>(dst) = u0;
        *reinterpret_cast<uint4*>(dst + 8) = u1;
        uint4 z = {0u, 0u, 0u, 0u};
        unsigned short* pz = P + (size_t)row * LDP + 4128 + ch;
        *reinterpret_cast<uint4*>(pz) = z;
        *reinterpret_cast<uint4*>(pz + 8) = z;
    } else if (bid < 1152) {                       // VWt[e][4096+c]=outb[c][e]; pad=0
        const int idx = (bid - 1056) * 256 + t;    // 768*32 = 24576
        const int e = idx >> 5, cc = idx & 31;
        VWt[(size_t)e * LDP + 4096 + cc] = f2bf(outb[cc * E_ + e]);
        VWt[(size_t)e * LDP + 4128 + cc] = 0;
    } else {                                       // zero out (4096x768 fp32; 768 blocks x 4096 floats)
        float* dst = out + (size_t)(bid - 1152) * 4096 + t * 16;
        const float4 z4 = make_float4(0.f, 0.f, 0.f, 0.f);
#pragma unroll
        for (int j = 0; j < 4; ++j)
            *reinterpret_cast<float4*>(dst + j * 4) = z4;
    }
}

// ---------------------------------------------------------------- K23: (merged) A2t + VWt builders
__global__ __launch_bounds__(768) void k23(const float* __restrict__ qp,
                                           const float* __restrict__ kk,
                                           const float* __restrict__ ow,
                                           const float* __restrict__ vv,
                                           unsigned short* __restrict__ A2t,
                                           float* __restrict__ abias,
                                           unsigned short* __restrict__ VWt) {
    const int c = blockIdx.x, h = blockIdx.y;
    const int t = threadIdx.x;
    __shared__ float kk_l[K_][DK];
    __shared__ float v_l[K_][DK];
    __shared__ float bq_l[DK];
    if (t < 512) {
        int k = t / DK, d = t % DK;
        kk_l[k][d] = kk[(size_t)(c * K_ + k) * G_ + h * DK + d];
        v_l[k][d]  = vv[(size_t)(c * K_ + k) * G_ + h * DK + d];
    }
    if (t < DK)
        bq_l[t] = qp[(size_t)(c * G_ + h * DK + t) * (DM + 1) + DM];
    __syncthreads();
    const int ch = c * H_ + h;
    {   // k3: VWt[e][n]
        const int e = t;
        float acc[K_];
#pragma unroll
        for (int k = 0; k < K_; ++k) acc[k] = 0.f;
        for (int d = 0; d < DK; ++d) {
            float w = ow[((size_t)ch * DK + d) * E_ + e];
#pragma unroll
            for (int k = 0; k < K_; ++k) acc[k] += w * v_l[k][d];
        }
#pragma unroll
        for (int k = 0; k < K_; ++k)
            VWt[(size_t)e * LDP + ch * 16 + k] = f2bf(acc[k]);
    }
    if (t < 256) {  // k2: A2t[n][m] (pre-scaled), abias
        const int m = t;
        float acc[K_];
#pragma unroll
        for (int k = 0; k < K_; ++k) acc[k] = 0.f;
        for (int d = 0; d < DK; ++d) {
            float wq = qp[(size_t)(c * G_ + h * DK + d) * (DM + 1) + m];
#pragma unroll
            for (int k = 0; k < K_; ++k) acc[k] += wq * kk_l[k][d];
        }
#pragma unroll
        for (int k = 0; k < K_; ++k)
            A2t[(size_t)(ch * 16 + k) * DM + m] = f2bf(acc[k] * SCL2);
        if (m < K_) {
            float s = 0.f;
#pragma unroll
            for (int d = 0; d < DK; ++d) s += bq_l[d] * kk_l[m][d];
            abias[ch * 16 + m] = s * SCL2;
        }
    }
}

// ---------------------------------------------------------------- K4: MFMA logits + exp2-softmax + prob scale -> P bf16
// BM(n)=128 x BN(bl)=256, BK=32; 3-buffer depth-2, counted vmcnt BEFORE pre-barrier, raw barriers
__global__ __launch_bounds__(256, 2) void k4_att(const unsigned short* __restrict__ A2t,
                                                 const unsigned short* __restrict__ tsb,
                                                 const float* __restrict__ abias,
                                                 const float* __restrict__ probs,
                                                 unsigned short* __restrict__ P) {
    const int n0  = blockIdx.x * 128;
    const int bl0 = blockIdx.y * 256;
    const int t = threadIdx.x;
    const int lane = t & 63, w = t >> 6;
    const int wr = w >> 1, wc = w & 1;
    const int c = lane & 15, g = lane >> 4;
    const int rsl = (c >> 1) & 3;

    __shared__ unsigned short a_l[3][128 * 32];    // 3 x 8 KB
    __shared__ unsigned short b_l[3][256 * 32];    // 3 x 16 KB
    __shared__ float ab_l[128];
    __shared__ float pb_l[256];

    if (t < 128) ab_l[t] = abias[n0 + t];
    pb_l[t] = probs[(size_t)(bl0 + t) * C_ + (n0 >> 7)];

    const int srow = t >> 2;
    const int sw = ((t & 3) ^ ((t >> 3) & 3)) * 8;

#define K4_STAGE(buf, kt)                                                         \
    {                                                                             \
        const int col_ = (kt) * 32 + sw;                                          \
        _Pragma("unroll")                                                         \
        for (int j = 0; j < 2; ++j)                                               \
            gl16(A2t + (size_t)(n0 + j * 64 + srow) * DM + col_,                  \
                 &a_l[buf][j * 2048 + t * 8]);                                    \
        _Pragma("unroll")                                                         \
        for (int j = 0; j < 4; ++j)                                               \
            gl16(tsb + (size_t)(bl0 + j * 64 + srow) * DM + col_,                 \
                 &b_l[buf][j * 2048 + t * 8]);                                    \
    }

    K4_STAGE(0, 0)
    K4_STAGE(1, 1)
    asm volatile("s_waitcnt lgkmcnt(0)" ::: "memory");   // pb/ab ds_writes published at first barrier

    f32x4 acc[4][8] = {};

#pragma unroll
    for (int kt = 0; kt < 8; ++kt) {
        const int bcur = kt % 3;
        if (kt < 6) {
            K4_STAGE((kt + 2) % 3, kt + 2)
            asm volatile("s_waitcnt vmcnt(12)" ::: "memory");   // tile kt arrived (mine)
        } else if (kt == 6) {
            asm volatile("s_waitcnt vmcnt(6)" ::: "memory");
        } else {
            asm volatile("s_waitcnt vmcnt(0)" ::: "memory");
        }
        asm volatile("s_barrier" ::: "memory");                 // PRE: tile kt visible to all
        bf16x8 af[4], bfr[8];
#pragma unroll
        for (int a = 0; a < 4; ++a)
            af[a] = *reinterpret_cast<const bf16x8*>(
                &a_l[bcur][(wr * 64 + a * 16 + c) * 32 + (g ^ rsl) * 8]);
#pragma unroll
        for (int b = 0; b < 8; ++b)
            bfr[b] = *reinterpret_cast<const bf16x8*>(
                &b_l[bcur][(wc * 128 + b * 16 + c) * 32 + (g ^ rsl) * 8]);
#pragma unroll
        for (int a = 0; a < 4; ++a)
#pragma unroll
            for (int b = 0; b < 8; ++b)
                acc[a][b] = __builtin_amdgcn_mfma_f32_16x16x32_bf16(af[a], bfr[b], acc[a][b], 0, 0, 0);
        if (kt < 7)
            asm volatile("s_barrier" ::: "memory");             // POST: buf[bcur] safe to overwrite
    }
#undef K4_STAGE

#pragma unroll
    for (int a = 0; a < 4; ++a) {
        const int nbase = wr * 64 + a * 16 + g * 4;
#pragma unroll
        for (int b = 0; b < 8; ++b) {
            const int bll = wc * 128 + b * 16 + c;
            float e0 = __builtin_amdgcn_exp2f(acc[a][b][0] + ab_l[nbase + 0]);
            float e1 = __builtin_amdgcn_exp2f(acc[a][b][1] + ab_l[nbase + 1]);
            float e2 = __builtin_amdgcn_exp2f(acc[a][b][2] + ab_l[nbase + 2]);
            float e3 = __builtin_amdgcn_exp2f(acc[a][b][3] + ab_l[nbase + 3]);
            float s = (e0 + e1) + (e2 + e3);
            s += __shfl_xor(s, 16);
            s += __shfl_xor(s, 32);
            const float pv = pb_l[bll] * __builtin_amdgcn_rcpf(s);
            unsigned r0, r1;
            float p0 = e0 * pv, p1 = e1 * pv, p2 = e2 * pv, p3 = e3 * pv;
            asm("v_cvt_pk_bf16_f32 %0, %1, %2" : "=v"(r0) : "v"(p0), "v"(p1));
            asm("v_cvt_pk_bf16_f32 %0, %1, %2" : "=v"(r1) : "v"(p2), "v"(p3));
            uint2 o; o.x = r0; o.y = r1;
            *reinterpret_cast<uint2*>(P + (size_t)(bl0 + bll) * LDP + n0 + nbase) = o;
        }
    }
}

// ---------------------------------------------------------------- K5: out += P(K-quarter) @ VWt^T  (fp32 atomics)
// BM=128, BN=192, BK=32; 3-buffer depth-2, counted vmcnt BEFORE pre-barrier, raw barriers
__global__ __launch_bounds__(256, 2) void k5_out(const unsigned short* __restrict__ P,
                                                 const unsigned short* __restrict__ VWt,
                                                 float* __restrict__ out) {
    const int wg = blockIdx.x;                     // 0..511
    const int xcd = wg & 7;
    const int local = wg >> 3;                     // 0..63
    const int bl0 = (xcd * 4 + (local & 3)) * 128;
    const int e0  = ((local >> 2) & 3) * 192;
    const int ks  = local >> 4;                    // 0..3

    const int t = threadIdx.x;
    const int lane = t & 63, w = t >> 6;
    const int wr = w >> 1, wc = w & 1;
    const int c = lane & 15, g = lane >> 4;
    const int rsl = (c >> 1) & 3;

    __shared__ unsigned short a_l[3][128 * 32];    // 3 x 8 KB
    __shared__ unsigned short b_l[3][192 * 32];    // 3 x 12 KB

    const int nstart = ks * 1024;
    const int nsteps = (ks == 3) ? 34 : 32;

    const int srow = t >> 2;
    const int sw = ((t & 3) ^ ((t >> 3) & 3)) * 8;

#define K5_STAGE(buf, kt)                                                         \
    {                                                                             \
        const int col_ = nstart + (kt) * 32 + sw;                                 \
        _Pragma("unroll")                                                         \
        for (int j = 0; j < 2; ++j)                                               \
            gl16(P + (size_t)(bl0 + j * 64 + srow) * LDP + col_,                  \
                 &a_l[buf][j * 2048 + t * 8]);                                    \
        _Pragma("unroll")                                                         \
        for (int j = 0; j < 3; ++j)                                               \
            gl16(VWt + (size_t)(e0 + j * 64 + srow) * LDP + col_,                 \
                 &b_l[buf][j * 2048 + t * 8]);                                    \
    }

    K5_STAGE(0, 0)
    K5_STAGE(1, 1)

    f32x4 acc[4][6] = {};
    for (int kt = 0; kt < nsteps; ++kt) {
        const int bcur = kt % 3;
        if (kt + 2 < nsteps) {
            K5_STAGE((kt + 2) % 3, kt + 2)
            asm volatile("s_waitcnt vmcnt(10)" ::: "memory");   // tile kt arrived (mine)
        } else if (kt + 1 < nsteps) {
            asm volatile("s_waitcnt vmcnt(5)" ::: "memory");
        } else {
            asm volatile("s_waitcnt vmcnt(0)" ::: "memory");
        }
        asm volatile("s_barrier" ::: "memory");                 // PRE: tile kt visible to all
        bf16x8 af[4], bfr[6];
#pragma unroll
        for (int a = 0; a < 4; ++a)
            af[a] = *reinterpret_cast<const bf16x8*>(
                &a_l[bcur][(wr * 64 + a * 16 + c) * 32 + (g ^ rsl) * 8]);
#pragma unroll
        for (int b = 0; b < 6; ++b)
            bfr[b] = *reinterpret_cast<const bf16x8*>(
                &b_l[bcur][(wc * 96 + b * 16 + c) * 32 + (g ^ rsl) * 8]);
#pragma unroll
        for (int a = 0; a < 4; ++a)
#pragma unroll
            for (int b = 0; b < 6; ++b)
                acc[a][b] = __builtin_amdgcn_mfma_f32_16x16x32_bf16(af[a], bfr[b], acc[a][b], 0, 0, 0);
        if (kt + 1 < nsteps)
            asm volatile("s_barrier" ::: "memory");             // POST: buf[bcur] safe to overwrite
    }
#undef K5_STAGE

    float* po = out + (size_t)bl0 * E_ + e0;
#pragma unroll
    for (int a = 0; a < 4; ++a)
#pragma unroll
        for (int b = 0; b < 6; ++b)
#pragma unroll
            for (int i = 0; i < 4; ++i)
                atomicAdd(po + (size_t)(wr * 64 + a * 16 + g * 4 + i) * E_ + wc * 96 + b * 16 + c,
                          acc[a][b][i]);
}

// ----------------------------------------------------------------
extern "C" void kernel_launch(void* const* d_in, const int* in_sizes, int n_in,
                              void* d_out, int out_size, void* d_ws, size_t ws_size,
                              hipStream_t stream) {
    const float* topk  = (const float*)d_in[0];
    const float* ts    = (const float*)d_in[1];
    const float* probs = (const float*)d_in[2];
    const float* qp    = (const float*)d_in[3];
    const float* kp    = (const float*)d_in[4];
    const float* vp    = (const float*)d_in[5];
    const float* ow    = (const float*)d_in[6];
    const float* ob    = (const float*)d_in[7];
    float* out = (float*)d_out;

    char* wp = (char*)d_ws;
    float* kk            = (float*)wp;           wp += 524288;
    float* vv            = (float*)wp;           wp += 524288;
    float* ab            = (float*)wp;           wp += 16384;
    unsigned short* tsb  = (unsigned short*)wp;  wp += 2097152;
    unsigned short* A2t  = (unsigned short*)wp;  wp += 2097152;
    unsigned short* VWt  = (unsigned short*)wp;  wp += (size_t)E_ * LDP * 2;   // 6,389,760
    unsigned short* P    = (unsigned short*)wp;  // 34,078,720

    k1_kv <<<dim3(32, 16), 256, 0, stream>>>(topk, kp, vp, kk, vv);
    k0_cvt<<<1920,         256, 0, stream>>>(ts, probs, ob, tsb, P, VWt, out);
    k23   <<<dim3(32, 8),  768, 0, stream>>>(qp, kk, ow, vv, A2t, ab, VWt);
    k4_att<<<dim3(32, 16), 256, 0, stream>>>(A2t, tsb, ab, probs, P);
    k5_out<<<512,          256, 0, stream>>>(P, VWt, out);
}

// Round 13
// 123.003 us; speedup vs baseline: 1.1400x; 1.1400x over previous
//
#include <hip/hip_runtime.h>
#include <hip/hip_bf16.h>

#define C_   32
#define K_   16
#define DLLM 768
#define DM   256
#define H_   8
#define DK   32
#define G_   256
#define BL   4096
#define NN   4096
#define E_   768
#define LDP  4160          // P / VWt row stride: 4096 + 32 bias-fold + 32 zero pad
#define TEMPF 0.17677669529663687f
#define SCL2  0.2550348647f   // TEMP * log2(e)

typedef __attribute__((ext_vector_type(8))) short bf16x8;
typedef __attribute__((ext_vector_type(4))) float f32x4;
typedef unsigned int u32;

__device__ __forceinline__ unsigned short f2bf(float f) {
    unsigned int u = __float_as_uint(f);
    unsigned int r = (u + 0x7fffu + ((u >> 16) & 1u)) >> 16;
    return (unsigned short)r;
}
__device__ __forceinline__ float bf2f(unsigned int u) {
    return __uint_as_float(u << 16);
}

// async global -> LDS, 16 bytes per lane (wave-uniform LDS base + lane*16)
__device__ __forceinline__ void gl16(const void* g, void* l) {
    __builtin_amdgcn_global_load_lds(
        (const __attribute__((address_space(1))) u32*)g,
        (__attribute__((address_space(3))) u32*)l, 16, 0, 0);
}

// ---------------------------------------------------------------- K1: kk/vv projections, coalesced wave-per-row
// 512 threads / 8 waves; block (c, gq) covers 32 g-rows -> topk re-read 8x (was 16x)
__global__ __launch_bounds__(512) void k1_kv(const float* __restrict__ topk,
                                             const float* __restrict__ kp,
                                             const float* __restrict__ vp,
                                             float* __restrict__ kk,
                                             float* __restrict__ vv) {
    const int c  = blockIdx.x;          // 0..31
    const int gq = blockIdx.y;          // 0..7
    const int t = threadIdx.x;
    const int lane = t & 63, w = t >> 6;

    __shared__ float t_l[K_][DLLM];     // 48 KB
    {
        const float4* src = reinterpret_cast<const float4*>(topk + (size_t)c * K_ * DLLM);
        float4* dst = reinterpret_cast<float4*>(&t_l[0][0]);
#pragma unroll
        for (int i = 0; i < 6; ++i)
            dst[t + i * 512] = src[t + i * 512];
    }
    __syncthreads();

#pragma unroll
    for (int gi = 0; gi < 4; ++gi) {
        const int g = gq * 32 + w * 4 + gi;
        const float* kpr = kp + (size_t)(c * G_ + g) * (DLLM + 1);
        const float* vpr = vp + (size_t)(c * G_ + g) * (DLLM + 1);
        const float bk = kpr[DLLM], bv = vpr[DLLM];
        float acck[K_] = {}, accv[K_] = {};
#pragma unroll
        for (int r = 0; r < 3; ++r) {
            const int d = r * 256 + lane * 4;
            float4 wk = *reinterpret_cast<const float4*>(kpr + d);
            float4 wv = *reinterpret_cast<const float4*>(vpr + d);
#pragma unroll
            for (int k = 0; k < K_; ++k) {
                float4 t4 = *reinterpret_cast<const float4*>(&t_l[k][d]);
                acck[k] += wk.x * t4.x + wk.y * t4.y + wk.z * t4.z + wk.w * t4.w;
                accv[k] += wv.x * t4.x + wv.y * t4.y + wv.z * t4.z + wv.w * t4.w;
            }
        }
#pragma unroll
        for (int s = 32; s >= 1; s >>= 1) {
#pragma unroll
            for (int k = 0; k < K_; ++k) {
                acck[k] += __shfl_xor(acck[k], s);
                accv[k] += __shfl_xor(accv[k], s);
            }
        }
        if (lane == 0) {
#pragma unroll
            for (int k = 0; k < K_; ++k) {
                kk[(size_t)(c * K_ + k) * G_ + g] = acck[k] + bk;
                vv[(size_t)(c * K_ + k) * G_ + g] = accv[k] + bv;
            }
        }
    }
}

// ---------------------------------------------------------------- k0: ts->bf16 + bias-fold + zero-pad columns of P and VWt
__global__ __launch_bounds__(256) void k0_cvt(const float* __restrict__ ts,
                                              const float* __restrict__ probs,
                                              const float* __restrict__ outb,
                                              unsigned short* __restrict__ tsb,
                                              unsigned short* __restrict__ P,
                                              unsigned short* __restrict__ VWt) {
    const int bid = blockIdx.x, t = threadIdx.x;
    if (bid < 1024) {                              // ts (4096x256) -> bf16
        const int idx = bid * 1024 + t * 4;
        float4 v = *reinterpret_cast<const float4*>(ts + idx);
        uint2 o;
        o.x = f2bf(v.x) | ((unsigned)f2bf(v.y) << 16);
        o.y = f2bf(v.z) | ((unsigned)f2bf(v.w) << 16);
        *reinterpret_cast<uint2*>(tsb + idx) = o;
    } else if (bid < 1056) {                       // P[:,4096+c]=probs, P[:,4128..4159]=0
        const int b2 = bid - 1024;
        const int row = b2 * 128 + (t >> 1);
        const int ch = (t & 1) * 16;
        unsigned short o[16];
#pragma unroll
        for (int j = 0; j < 16; ++j) o[j] = f2bf(probs[row * 32 + ch + j]);
        uint4 u0, u1;
        u0.x = o[0] | (o[1] << 16);  u0.y = o[2] | (o[3] << 16);
        u0.z = o[4] | (o[5] << 16);  u0.w = o[6] | (o[7] << 16);
        u1.x = o[8] | (o[9] << 16);  u1.y = o[10] | (o[11] << 16);
        u1.z = o[12] | (o[13] << 16); u1.w = o[14] | (o[15] << 16);
        unsigned short* dst = P + (size_t)row * LDP + 4096 + ch;
        *reinterpret_cast<uint4*>(dst) = u0;
        *reinterpret_cast<uint4*>(dst + 8) = u1;
        uint4 z = {0u, 0u, 0u, 0u};
        unsigned short* pz = P + (size_t)row * LDP + 4128 + ch;
        *reinterpret_cast<uint4*>(pz) = z;
        *reinterpret_cast<uint4*>(pz + 8) = z;
    } else {                                       // VWt[e][4096+c]=outb[c][e]; pad=0
        const int idx = (bid - 1056) * 256 + t;    // 768*32 = 24576
        const int e = idx >> 5, cc = idx & 31;
        VWt[(size_t)e * LDP + 4096 + cc] = f2bf(outb[cc * E_ + e]);
        VWt[(size_t)e * LDP + 4128 + cc] = 0;
    }
}

// ---------------------------------------------------------------- K23: (merged) A2t + VWt builders
__global__ __launch_bounds__(768) void k23(const float* __restrict__ qp,
                                           const float* __restrict__ kk,
                                           const float* __restrict__ ow,
                                           const float* __restrict__ vv,
                                           unsigned short* __restrict__ A2t,
                                           float* __restrict__ abias,
                                           unsigned short* __restrict__ VWt) {
    const int c = blockIdx.x, h = blockIdx.y;
    const int t = threadIdx.x;
    __shared__ float kk_l[K_][DK];
    __shared__ float v_l[K_][DK];
    __shared__ float bq_l[DK];
    if (t < 512) {
        int k = t / DK, d = t % DK;
        kk_l[k][d] = kk[(size_t)(c * K_ + k) * G_ + h * DK + d];
        v_l[k][d]  = vv[(size_t)(c * K_ + k) * G_ + h * DK + d];
    }
    if (t < DK)
        bq_l[t] = qp[(size_t)(c * G_ + h * DK + t) * (DM + 1) + DM];
    __syncthreads();
    const int ch = c * H_ + h;
    {   // k3: VWt[e][n]
        const int e = t;
        float acc[K_];
#pragma unroll
        for (int k = 0; k < K_; ++k) acc[k] = 0.f;
        for (int d = 0; d < DK; ++d) {
            float w = ow[((size_t)ch * DK + d) * E_ + e];
#pragma unroll
            for (int k = 0; k < K_; ++k) acc[k] += w * v_l[k][d];
        }
#pragma unroll
        for (int k = 0; k < K_; ++k)
            VWt[(size_t)e * LDP + ch * 16 + k] = f2bf(acc[k]);
    }
    if (t < 256) {  // k2: A2t[n][m] (pre-scaled), abias
        const int m = t;
        float acc[K_];
#pragma unroll
        for (int k = 0; k < K_; ++k) acc[k] = 0.f;
        for (int d = 0; d < DK; ++d) {
            float wq = qp[(size_t)(c * G_ + h * DK + d) * (DM + 1) + m];
#pragma unroll
            for (int k = 0; k < K_; ++k) acc[k] += wq * kk_l[k][d];
        }
#pragma unroll
        for (int k = 0; k < K_; ++k)
            A2t[(size_t)(ch * 16 + k) * DM + m] = f2bf(acc[k] * SCL2);
        if (m < K_) {
            float s = 0.f;
#pragma unroll
            for (int d = 0; d < DK; ++d) s += bq_l[d] * kk_l[m][d];
            abias[ch * 16 + m] = s * SCL2;
        }
    }
}

// ---------------------------------------------------------------- K4: MFMA logits + exp2-softmax + prob scale -> P bf16
// BM(n)=128 x BN(bl)=256, BK=32; 3-buffer depth-2, counted vmcnt BEFORE pre-barrier (round-11 known-good)
__global__ __launch_bounds__(256, 2) void k4_att(const unsigned short* __restrict__ A2t,
                                                 const unsigned short* __restrict__ tsb,
                                                 const float* __restrict__ abias,
                                                 const float* __restrict__ probs,
                                                 unsigned short* __restrict__ P) {
    const int n0  = blockIdx.x * 128;
    const int bl0 = blockIdx.y * 256;
    const int t = threadIdx.x;
    const int lane = t & 63, w = t >> 6;
    const int wr = w >> 1, wc = w & 1;
    const int c = lane & 15, g = lane >> 4;
    const int rsl = (c >> 1) & 3;

    __shared__ unsigned short a_l[3][128 * 32];    // 3 x 8 KB
    __shared__ unsigned short b_l[3][256 * 32];    // 3 x 16 KB
    __shared__ float ab_l[128];
    __shared__ float pb_l[256];

    if (t < 128) ab_l[t] = abias[n0 + t];
    pb_l[t] = probs[(size_t)(bl0 + t) * C_ + (n0 >> 7)];

    const int srow = t >> 2;
    const int sw = ((t & 3) ^ ((t >> 3) & 3)) * 8;

#define K4_STAGE(buf, kt)                                                         \
    {                                                                             \
        const int col_ = (kt) * 32 + sw;                                          \
        _Pragma("unroll")                                                         \
        for (int j = 0; j < 2; ++j)                                               \
            gl16(A2t + (size_t)(n0 + j * 64 + srow) * DM + col_,                  \
                 &a_l[buf][j * 2048 + t * 8]);                                    \
        _Pragma("unroll")                                                         \
        for (int j = 0; j < 4; ++j)                                               \
            gl16(tsb + (size_t)(bl0 + j * 64 + srow) * DM + col_,                 \
                 &b_l[buf][j * 2048 + t * 8]);                                    \
    }

    K4_STAGE(0, 0)
    K4_STAGE(1, 1)
    asm volatile("s_waitcnt lgkmcnt(0)" ::: "memory");   // pb/ab ds_writes published at first barrier

    f32x4 acc[4][8] = {};

#pragma unroll
    for (int kt = 0; kt < 8; ++kt) {
        const int bcur = kt % 3;
        if (kt < 6) {
            K4_STAGE((kt + 2) % 3, kt + 2)
            asm volatile("s_waitcnt vmcnt(12)" ::: "memory");   // tile kt arrived (mine)
        } else if (kt == 6) {
            asm volatile("s_waitcnt vmcnt(6)" ::: "memory");
        } else {
            asm volatile("s_waitcnt vmcnt(0)" ::: "memory");
        }
        asm volatile("s_barrier" ::: "memory");                 // PRE: tile kt visible to all
        bf16x8 af[4], bfr[8];
#pragma unroll
        for (int a = 0; a < 4; ++a)
            af[a] = *reinterpret_cast<const bf16x8*>(
                &a_l[bcur][(wr * 64 + a * 16 + c) * 32 + (g ^ rsl) * 8]);
#pragma unroll
        for (int b = 0; b < 8; ++b)
            bfr[b] = *reinterpret_cast<const bf16x8*>(
                &b_l[bcur][(wc * 128 + b * 16 + c) * 32 + (g ^ rsl) * 8]);
#pragma unroll
        for (int a = 0; a < 4; ++a)
#pragma unroll
            for (int b = 0; b < 8; ++b)
                acc[a][b] = __builtin_amdgcn_mfma_f32_16x16x32_bf16(af[a], bfr[b], acc[a][b], 0, 0, 0);
        if (kt < 7)
            asm volatile("s_barrier" ::: "memory");             // POST: buf[bcur] safe to overwrite
    }
#undef K4_STAGE

#pragma unroll
    for (int a = 0; a < 4; ++a) {
        const int nbase = wr * 64 + a * 16 + g * 4;
#pragma unroll
        for (int b = 0; b < 8; ++b) {
            const int bll = wc * 128 + b * 16 + c;
            float e0 = __builtin_amdgcn_exp2f(acc[a][b][0] + ab_l[nbase + 0]);
            float e1 = __builtin_amdgcn_exp2f(acc[a][b][1] + ab_l[nbase + 1]);
            float e2 = __builtin_amdgcn_exp2f(acc[a][b][2] + ab_l[nbase + 2]);
            float e3 = __builtin_amdgcn_exp2f(acc[a][b][3] + ab_l[nbase + 3]);
            float s = (e0 + e1) + (e2 + e3);
            s += __shfl_xor(s, 16);
            s += __shfl_xor(s, 32);
            const float pv = pb_l[bll] * __builtin_amdgcn_rcpf(s);
            unsigned r0, r1;
            float p0 = e0 * pv, p1 = e1 * pv, p2 = e2 * pv, p3 = e3 * pv;
            asm("v_cvt_pk_bf16_f32 %0, %1, %2" : "=v"(r0) : "v"(p0), "v"(p1));
            asm("v_cvt_pk_bf16_f32 %0, %1, %2" : "=v"(r1) : "v"(p2), "v"(p3));
            uint2 o; o.x = r0; o.y = r1;
            *reinterpret_cast<uint2*>(P + (size_t)(bl0 + bll) * LDP + n0 + nbase) = o;
        }
    }
}

// ---------------------------------------------------------------- K5: part[ks] = P(K-sixth) @ VWt^T  (bf16 partials)
// BM=128, BN=192, BK=32; 2-buffer depth-1 counted vmcnt; split-K=6 -> 768 blocks = 3/CU
__global__ __launch_bounds__(256, 3) void k5_out(const unsigned short* __restrict__ P,
                                                 const unsigned short* __restrict__ VWt,
                                                 unsigned short* __restrict__ part) {
    const int wg = blockIdx.x;                     // 0..767
    const int xcd = wg & 7;
    const int local = wg >> 3;                     // 0..95 = 4 bl x 4 e x 6 ks
    const int bl0 = (xcd * 4 + (local & 3)) * 128;
    const int e0  = ((local >> 2) & 3) * 192;
    const int ks  = local >> 4;                    // 0..5

    const int t = threadIdx.x;
    const int lane = t & 63, w = t >> 6;
    const int wr = w >> 1, wc = w & 1;
    const int c = lane & 15, g = lane >> 4;
    const int rsl = (c >> 1) & 3;

    __shared__ unsigned short a_l[2][128 * 32];    // 2 x 8 KB
    __shared__ unsigned short b_l[2][192 * 32];    // 2 x 12 KB

    const int nstart = ks * 704;                   // 22 steps x 32; last gets 20
    const int nsteps = (ks == 5) ? 20 : 22;

    const int srow = t >> 2;
    const int sw = ((t & 3) ^ ((t >> 3) & 3)) * 8;

#define K5_STAGE(buf, kt)                                                         \
    {                                                                             \
        const int col_ = nstart + (kt) * 32 + sw;                                 \
        _Pragma("unroll")                                                         \
        for (int j = 0; j < 2; ++j)                                               \
            gl16(P + (size_t)(bl0 + j * 64 + srow) * LDP + col_,                  \
                 &a_l[buf][j * 2048 + t * 8]);                                    \
        _Pragma("unroll")                                                         \
        for (int j = 0; j < 3; ++j)                                               \
            gl16(VWt + (size_t)(e0 + j * 64 + srow) * LDP + col_,                 \
                 &b_l[buf][j * 2048 + t * 8]);                                    \
    }

    K5_STAGE(0, 0)

    f32x4 acc[4][6] = {};
    for (int kt = 0; kt < nsteps; ++kt) {
        const int bcur = kt & 1;
        if (kt + 1 < nsteps) {
            K5_STAGE(bcur ^ 1, kt + 1)
            asm volatile("s_waitcnt vmcnt(5)" ::: "memory");    // tile kt arrived (mine)
        } else {
            asm volatile("s_waitcnt vmcnt(0)" ::: "memory");
        }
        asm volatile("s_barrier" ::: "memory");                 // PRE: tile kt visible to all
        bf16x8 af[4], bfr[6];
#pragma unroll
        for (int a = 0; a < 4; ++a)
            af[a] = *reinterpret_cast<const bf16x8*>(
                &a_l[bcur][(wr * 64 + a * 16 + c) * 32 + (g ^ rsl) * 8]);
#pragma unroll
        for (int b = 0; b < 6; ++b)
            bfr[b] = *reinterpret_cast<const bf16x8*>(
                &b_l[bcur][(wc * 96 + b * 16 + c) * 32 + (g ^ rsl) * 8]);
#pragma unroll
        for (int a = 0; a < 4; ++a)
#pragma unroll
            for (int b = 0; b < 6; ++b)
                acc[a][b] = __builtin_amdgcn_mfma_f32_16x16x32_bf16(af[a], bfr[b], acc[a][b], 0, 0, 0);
        if (kt + 1 < nsteps)
            asm volatile("s_barrier" ::: "memory");             // POST: buf[bcur^1]... next stage overwrites buf[bcur] at kt+1 only after this
    }
#undef K5_STAGE

    unsigned short* pp = part + ((size_t)ks * BL + bl0) * E_ + e0;
#pragma unroll
    for (int a = 0; a < 4; ++a)
#pragma unroll
        for (int b = 0; b < 6; ++b)
#pragma unroll
            for (int i = 0; i < 4; ++i)
                pp[(size_t)(wr * 64 + a * 16 + g * 4 + i) * E_ + wc * 96 + b * 16 + c] =
                    f2bf(acc[a][b][i]);
}

// ---------------------------------------------------------------- k6: out = sum of 6 bf16 partials
__global__ __launch_bounds__(256) void k6_red(const unsigned short* __restrict__ part,
                                              float* __restrict__ out) {
    const size_t base = ((size_t)blockIdx.x * 256 + threadIdx.x) * 8;
    float s[8] = {};
#pragma unroll
    for (int ks = 0; ks < 6; ++ks) {
        uint4 v = *reinterpret_cast<const uint4*>(part + (size_t)ks * (BL * E_) + base);
        const unsigned u[4] = {v.x, v.y, v.z, v.w};
#pragma unroll
        for (int j = 0; j < 4; ++j) {
            s[2 * j]     += bf2f(u[j] & 0xffffu);
            s[2 * j + 1] += bf2f(u[j] >> 16);
        }
    }
    *reinterpret_cast<float4*>(out + base)     = make_float4(s[0], s[1], s[2], s[3]);
    *reinterpret_cast<float4*>(out + base + 4) = make_float4(s[4], s[5], s[6], s[7]);
}

// ----------------------------------------------------------------
extern "C" void kernel_launch(void* const* d_in, const int* in_sizes, int n_in,
                              void* d_out, int out_size, void* d_ws, size_t ws_size,
                              hipStream_t stream) {
    const float* topk  = (const float*)d_in[0];
    const float* ts    = (const float*)d_in[1];
    const float* probs = (const float*)d_in[2];
    const float* qp    = (const float*)d_in[3];
    const float* kp    = (const float*)d_in[4];
    const float* vp    = (const float*)d_in[5];
    const float* ow    = (const float*)d_in[6];
    const float* ob    = (const float*)d_in[7];
    float* out = (float*)d_out;

    char* wp = (char*)d_ws;
    float* kk            = (float*)wp;           wp += 524288;
    float* vv            = (float*)wp;           wp += 524288;
    float* ab            = (float*)wp;           wp += 16384;
    unsigned short* tsb  = (unsigned short*)wp;  wp += 2097152;
    unsigned short* A2t  = (unsigned short*)wp;  wp += 2097152;
    unsigned short* VWt  = (unsigned short*)wp;  wp += (size_t)E_ * LDP * 2;   // 6,389,760
    unsigned short* P    = (unsigned short*)wp;  wp += (size_t)BL * LDP * 2;   // 34,078,720
    unsigned short* part = (unsigned short*)wp;  // 6 * 4096*768*2 = 37,748,736

    k1_kv <<<dim3(32, 8),  512, 0, stream>>>(topk, kp, vp, kk, vv);
    k0_cvt<<<1152,         256, 0, stream>>>(ts, probs, ob, tsb, P, VWt);
    k23   <<<dim3(32, 8),  768, 0, stream>>>(qp, kk, ow, vv, A2t, ab, VWt);
    k4_att<<<dim3(32, 16), 256, 0, stream>>>(A2t, tsb, ab, probs, P);
    k5_out<<<768,          256, 0, stream>>>(P, VWt, part);
    k6_red<<<1536,         256, 0, stream>>>(part, out);
}

// Round 14
// 113.823 us; speedup vs baseline: 1.2320x; 1.0807x over previous
//
#include <hip/hip_runtime.h>
#include <hip/hip_bf16.h>

#define C_   32
#define K_   16
#define DLLM 768
#define DM   256
#define H_   8
#define DK   32
#define G_   256
#define BL   4096
#define NN   4096
#define E_   768
#define LDP  4160          // P / VWt row stride: 4096 + 32 bias-fold + 32 zero pad
#define TEMPF 0.17677669529663687f
#define SCL2  0.2550348647f   // TEMP * log2(e)

typedef __attribute__((ext_vector_type(8))) short bf16x8;
typedef __attribute__((ext_vector_type(4))) float f32x4;
typedef unsigned int u32;

__device__ __forceinline__ unsigned short f2bf(float f) {
    unsigned int u = __float_as_uint(f);
    unsigned int r = (u + 0x7fffu + ((u >> 16) & 1u)) >> 16;
    return (unsigned short)r;
}
__device__ __forceinline__ float bf2f(unsigned int u) {
    return __uint_as_float(u << 16);
}

// async global -> LDS, 16 bytes per lane (wave-uniform LDS base + lane*16)
__device__ __forceinline__ void gl16(const void* g, void* l) {
    __builtin_amdgcn_global_load_lds(
        (const __attribute__((address_space(1))) u32*)g,
        (__attribute__((address_space(3))) u32*)l, 16, 0, 0);
}

// ---------------------------------------------------------------- K1: kk/vv projections, coalesced + reg-prefetch
// 256 threads, grid (32,16) = 512 blocks (2/CU). Wave owns 4 g-rows; loads for g-row gi+1
// are issued BEFORE computing gi (6 float4 in flight covering the FMA+LDS phase).
__global__ __launch_bounds__(256) void k1_kv(const float* __restrict__ topk,
                                             const float* __restrict__ kp,
                                             const float* __restrict__ vp,
                                             float* __restrict__ kk,
                                             float* __restrict__ vv) {
    const int c  = blockIdx.x;          // 0..31
    const int gq = blockIdx.y;          // 0..15
    const int t = threadIdx.x;
    const int lane = t & 63, w = t >> 6;

    __shared__ float t_l[K_][DLLM];     // 48 KB
    {
        const float4* src = reinterpret_cast<const float4*>(topk + (size_t)c * K_ * DLLM);
        float4* dst = reinterpret_cast<float4*>(&t_l[0][0]);
#pragma unroll
        for (int i = 0; i < 12; ++i)
            dst[t + i * 256] = src[t + i * 256];
    }
    __syncthreads();

    const int g0 = gq * 16 + w * 4;
    const int dbase = lane * 4;

    float4 ck[3], cv[3], nk[3], nv[3];
    {
        const float* kpr = kp + (size_t)(c * G_ + g0) * (DLLM + 1);
        const float* vpr = vp + (size_t)(c * G_ + g0) * (DLLM + 1);
#pragma unroll
        for (int r = 0; r < 3; ++r) {
            ck[r] = *reinterpret_cast<const float4*>(kpr + r * 256 + dbase);
            cv[r] = *reinterpret_cast<const float4*>(vpr + r * 256 + dbase);
        }
    }

#pragma unroll
    for (int gi = 0; gi < 4; ++gi) {
        const int g = g0 + gi;
        const float* kpr = kp + (size_t)(c * G_ + g) * (DLLM + 1);
        const float* vpr = vp + (size_t)(c * G_ + g) * (DLLM + 1);
        if (gi < 3) {   // prefetch next g-row while computing this one
            const float* kpn = kpr + (DLLM + 1);
            const float* vpn = vpr + (DLLM + 1);
#pragma unroll
            for (int r = 0; r < 3; ++r) {
                nk[r] = *reinterpret_cast<const float4*>(kpn + r * 256 + dbase);
                nv[r] = *reinterpret_cast<const float4*>(vpn + r * 256 + dbase);
            }
        }
        const float bk = kpr[DLLM], bv = vpr[DLLM];
        float acck[K_] = {}, accv[K_] = {};
#pragma unroll
        for (int r = 0; r < 3; ++r) {
            const int d = r * 256 + dbase;
#pragma unroll
            for (int k = 0; k < K_; ++k) {
                float4 t4 = *reinterpret_cast<const float4*>(&t_l[k][d]);
                acck[k] += ck[r].x * t4.x + ck[r].y * t4.y + ck[r].z * t4.z + ck[r].w * t4.w;
                accv[k] += cv[r].x * t4.x + cv[r].y * t4.y + cv[r].z * t4.z + cv[r].w * t4.w;
            }
        }
#pragma unroll
        for (int s = 32; s >= 1; s >>= 1) {
#pragma unroll
            for (int k = 0; k < K_; ++k) {
                acck[k] += __shfl_xor(acck[k], s);
                accv[k] += __shfl_xor(accv[k], s);
            }
        }
        if (lane == 0) {
#pragma unroll
            for (int k = 0; k < K_; ++k) {
                kk[(size_t)(c * K_ + k) * G_ + g] = acck[k] + bk;
                vv[(size_t)(c * K_ + k) * G_ + g] = accv[k] + bv;
            }
        }
#pragma unroll
        for (int r = 0; r < 3; ++r) { ck[r] = nk[r]; cv[r] = nv[r]; }
    }
}

// ---------------------------------------------------------------- k0: ts->bf16 + bias-fold + zero-pad columns of P and VWt
__global__ __launch_bounds__(256) void k0_cvt(const float* __restrict__ ts,
                                              const float* __restrict__ probs,
                                              const float* __restrict__ outb,
                                              unsigned short* __restrict__ tsb,
                                              unsigned short* __restrict__ P,
                                              unsigned short* __restrict__ VWt) {
    const int bid = blockIdx.x, t = threadIdx.x;
    if (bid < 1024) {                              // ts (4096x256) -> bf16
        const int idx = bid * 1024 + t * 4;
        float4 v = *reinterpret_cast<const float4*>(ts + idx);
        uint2 o;
        o.x = f2bf(v.x) | ((unsigned)f2bf(v.y) << 16);
        o.y = f2bf(v.z) | ((unsigned)f2bf(v.w) << 16);
        *reinterpret_cast<uint2*>(tsb + idx) = o;
    } else if (bid < 1056) {                       // P[:,4096+c]=probs, P[:,4128..4159]=0
        const int b2 = bid - 1024;
        const int row = b2 * 128 + (t >> 1);
        const int ch = (t & 1) * 16;
        unsigned short o[16];
#pragma unroll
        for (int j = 0; j < 16; ++j) o[j] = f2bf(probs[row * 32 + ch + j]);
        uint4 u0, u1;
        u0.x = o[0] | (o[1] << 16);  u0.y = o[2] | (o[3] << 16);
        u0.z = o[4] | (o[5] << 16);  u0.w = o[6] | (o[7] << 16);
        u1.x = o[8] | (o[9] << 16);  u1.y = o[10] | (o[11] << 16);
        u1.z = o[12] | (o[13] << 16); u1.w = o[14] | (o[15] << 16);
        unsigned short* dst = P + (size_t)row * LDP + 4096 + ch;
        *reinterpret_cast<uint4*>(dst) = u0;
        *reinterpret_cast<uint4*>(dst + 8) = u1;
        uint4 z = {0u, 0u, 0u, 0u};
        unsigned short* pz = P + (size_t)row * LDP + 4128 + ch;
        *reinterpret_cast<uint4*>(pz) = z;
        *reinterpret_cast<uint4*>(pz + 8) = z;
    } else {                                       // VWt[e][4096+c]=outb[c][e]; pad=0
        const int idx = (bid - 1056) * 256 + t;    // 768*32 = 24576
        const int e = idx >> 5, cc = idx & 31;
        VWt[(size_t)e * LDP + 4096 + cc] = f2bf(outb[cc * E_ + e]);
        VWt[(size_t)e * LDP + 4128 + cc] = 0;
    }
}

// ---------------------------------------------------------------- K23: (merged) A2t + VWt builders
__global__ __launch_bounds__(768) void k23(const float* __restrict__ qp,
                                           const float* __restrict__ kk,
                                           const float* __restrict__ ow,
                                           const float* __restrict__ vv,
                                           unsigned short* __restrict__ A2t,
                                           float* __restrict__ abias,
                                           unsigned short* __restrict__ VWt) {
    const int c = blockIdx.x, h = blockIdx.y;
    const int t = threadIdx.x;
    __shared__ float kk_l[K_][DK];
    __shared__ float v_l[K_][DK];
    __shared__ float bq_l[DK];
    if (t < 512) {
        int k = t / DK, d = t % DK;
        kk_l[k][d] = kk[(size_t)(c * K_ + k) * G_ + h * DK + d];
        v_l[k][d]  = vv[(size_t)(c * K_ + k) * G_ + h * DK + d];
    }
    if (t < DK)
        bq_l[t] = qp[(size_t)(c * G_ + h * DK + t) * (DM + 1) + DM];
    __syncthreads();
    const int ch = c * H_ + h;
    {   // k3: VWt[e][n]
        const int e = t;
        float acc[K_];
#pragma unroll
        for (int k = 0; k < K_; ++k) acc[k] = 0.f;
        for (int d = 0; d < DK; ++d) {
            float w = ow[((size_t)ch * DK + d) * E_ + e];
#pragma unroll
            for (int k = 0; k < K_; ++k) acc[k] += w * v_l[k][d];
        }
#pragma unroll
        for (int k = 0; k < K_; ++k)
            VWt[(size_t)e * LDP + ch * 16 + k] = f2bf(acc[k]);
    }
    if (t < 256) {  // k2: A2t[n][m] (pre-scaled), abias
        const int m = t;
        float acc[K_];
#pragma unroll
        for (int k = 0; k < K_; ++k) acc[k] = 0.f;
        for (int d = 0; d < DK; ++d) {
            float wq = qp[(size_t)(c * G_ + h * DK + d) * (DM + 1) + m];
#pragma unroll
            for (int k = 0; k < K_; ++k) acc[k] += wq * kk_l[k][d];
        }
#pragma unroll
        for (int k = 0; k < K_; ++k)
            A2t[(size_t)(ch * 16 + k) * DM + m] = f2bf(acc[k] * SCL2);
        if (m < K_) {
            float s = 0.f;
#pragma unroll
            for (int d = 0; d < DK; ++d) s += bq_l[d] * kk_l[m][d];
            abias[ch * 16 + m] = s * SCL2;
        }
    }
}

// ---------------------------------------------------------------- K4: MFMA logits + exp2-softmax + prob scale -> P bf16
// BM(n)=128 x BN(bl)=256, BK=32; 3-buffer depth-2, counted vmcnt BEFORE pre-barrier (round-11 known-good)
__global__ __launch_bounds__(256, 2) void k4_att(const unsigned short* __restrict__ A2t,
                                                 const unsigned short* __restrict__ tsb,
                                                 const float* __restrict__ abias,
                                                 const float* __restrict__ probs,
                                                 unsigned short* __restrict__ P) {
    const int n0  = blockIdx.x * 128;
    const int bl0 = blockIdx.y * 256;
    const int t = threadIdx.x;
    const int lane = t & 63, w = t >> 6;
    const int wr = w >> 1, wc = w & 1;
    const int c = lane & 15, g = lane >> 4;
    const int rsl = (c >> 1) & 3;

    __shared__ unsigned short a_l[3][128 * 32];    // 3 x 8 KB
    __shared__ unsigned short b_l[3][256 * 32];    // 3 x 16 KB
    __shared__ float ab_l[128];
    __shared__ float pb_l[256];

    if (t < 128) ab_l[t] = abias[n0 + t];
    pb_l[t] = probs[(size_t)(bl0 + t) * C_ + (n0 >> 7)];

    const int srow = t >> 2;
    const int sw = ((t & 3) ^ ((t >> 3) & 3)) * 8;

#define K4_STAGE(buf, kt)                                                         \
    {                                                                             \
        const int col_ = (kt) * 32 + sw;                                          \
        _Pragma("unroll")                                                         \
        for (int j = 0; j < 2; ++j)                                               \
            gl16(A2t + (size_t)(n0 + j * 64 + srow) * DM + col_,                  \
                 &a_l[buf][j * 2048 + t * 8]);                                    \
        _Pragma("unroll")                                                         \
        for (int j = 0; j < 4; ++j)                                               \
            gl16(tsb + (size_t)(bl0 + j * 64 + srow) * DM + col_,                 \
                 &b_l[buf][j * 2048 + t * 8]);                                    \
    }

    K4_STAGE(0, 0)
    K4_STAGE(1, 1)
    asm volatile("s_waitcnt lgkmcnt(0)" ::: "memory");   // pb/ab ds_writes published at first barrier

    f32x4 acc[4][8] = {};

#pragma unroll
    for (int kt = 0; kt < 8; ++kt) {
        const int bcur = kt % 3;
        if (kt < 6) {
            K4_STAGE((kt + 2) % 3, kt + 2)
            asm volatile("s_waitcnt vmcnt(12)" ::: "memory");   // tile kt arrived (mine)
        } else if (kt == 6) {
            asm volatile("s_waitcnt vmcnt(6)" ::: "memory");
        } else {
            asm volatile("s_waitcnt vmcnt(0)" ::: "memory");
        }
        asm volatile("s_barrier" ::: "memory");                 // PRE: tile kt visible to all
        bf16x8 af[4], bfr[8];
#pragma unroll
        for (int a = 0; a < 4; ++a)
            af[a] = *reinterpret_cast<const bf16x8*>(
                &a_l[bcur][(wr * 64 + a * 16 + c) * 32 + (g ^ rsl) * 8]);
#pragma unroll
        for (int b = 0; b < 8; ++b)
            bfr[b] = *reinterpret_cast<const bf16x8*>(
                &b_l[bcur][(wc * 128 + b * 16 + c) * 32 + (g ^ rsl) * 8]);
#pragma unroll
        for (int a = 0; a < 4; ++a)
#pragma unroll
            for (int b = 0; b < 8; ++b)
                acc[a][b] = __builtin_amdgcn_mfma_f32_16x16x32_bf16(af[a], bfr[b], acc[a][b], 0, 0, 0);
        if (kt < 7)
            asm volatile("s_barrier" ::: "memory");             // POST: buf[bcur] safe to overwrite
    }
#undef K4_STAGE

#pragma unroll
    for (int a = 0; a < 4; ++a) {
        const int nbase = wr * 64 + a * 16 + g * 4;
#pragma unroll
        for (int b = 0; b < 8; ++b) {
            const int bll = wc * 128 + b * 16 + c;
            float e0 = __builtin_amdgcn_exp2f(acc[a][b][0] + ab_l[nbase + 0]);
            float e1 = __builtin_amdgcn_exp2f(acc[a][b][1] + ab_l[nbase + 1]);
            float e2 = __builtin_amdgcn_exp2f(acc[a][b][2] + ab_l[nbase + 2]);
            float e3 = __builtin_amdgcn_exp2f(acc[a][b][3] + ab_l[nbase + 3]);
            float s = (e0 + e1) + (e2 + e3);
            s += __shfl_xor(s, 16);
            s += __shfl_xor(s, 32);
            const float pv = pb_l[bll] * __builtin_amdgcn_rcpf(s);
            unsigned r0, r1;
            float p0 = e0 * pv, p1 = e1 * pv, p2 = e2 * pv, p3 = e3 * pv;
            asm("v_cvt_pk_bf16_f32 %0, %1, %2" : "=v"(r0) : "v"(p0), "v"(p1));
            asm("v_cvt_pk_bf16_f32 %0, %1, %2" : "=v"(r1) : "v"(p2), "v"(p3));
            uint2 o; o.x = r0; o.y = r1;
            *reinterpret_cast<uint2*>(P + (size_t)(bl0 + bll) * LDP + n0 + nbase) = o;
        }
    }
}

// ---------------------------------------------------------------- K5: part[ks] = P(K-sixth) @ VWt^T  (bf16 partials)
// BM=128, BN=192, BK=32; 2-buffer depth-1 counted vmcnt; split-K=6 -> 768 blocks = 3/CU
__global__ __launch_bounds__(256, 3) void k5_out(const unsigned short* __restrict__ P,
                                                 const unsigned short* __restrict__ VWt,
                                                 unsigned short* __restrict__ part) {
    const int wg = blockIdx.x;                     // 0..767
    const int xcd = wg & 7;
    const int local = wg >> 3;                     // 0..95 = 4 bl x 4 e x 6 ks
    const int bl0 = (xcd * 4 + (local & 3)) * 128;
    const int e0  = ((local >> 2) & 3) * 192;
    const int ks  = local >> 4;                    // 0..5

    const int t = threadIdx.x;
    const int lane = t & 63, w = t >> 6;
    const int wr = w >> 1, wc = w & 1;
    const int c = lane & 15, g = lane >> 4;
    const int rsl = (c >> 1) & 3;

    __shared__ unsigned short a_l[2][128 * 32];    // 2 x 8 KB
    __shared__ unsigned short b_l[2][192 * 32];    // 2 x 12 KB

    const int nstart = ks * 704;                   // 22 steps x 32; last gets 20
    const int nsteps = (ks == 5) ? 20 : 22;

    const int srow = t >> 2;
    const int sw = ((t & 3) ^ ((t >> 3) & 3)) * 8;

#define K5_STAGE(buf, kt)                                                         \
    {                                                                             \
        const int col_ = nstart + (kt) * 32 + sw;                                 \
        _Pragma("unroll")                                                         \
        for (int j = 0; j < 2; ++j)                                               \
            gl16(P + (size_t)(bl0 + j * 64 + srow) * LDP + col_,                  \
                 &a_l[buf][j * 2048 + t * 8]);                                    \
        _Pragma("unroll")                                                         \
        for (int j = 0; j < 3; ++j)                                               \
            gl16(VWt + (size_t)(e0 + j * 64 + srow) * LDP + col_,                 \
                 &b_l[buf][j * 2048 + t * 8]);                                    \
    }

    K5_STAGE(0, 0)

    f32x4 acc[4][6] = {};
    for (int kt = 0; kt < nsteps; ++kt) {
        const int bcur = kt & 1;
        if (kt + 1 < nsteps) {
            K5_STAGE(bcur ^ 1, kt + 1)
            asm volatile("s_waitcnt vmcnt(5)" ::: "memory");    // tile kt arrived (mine)
        } else {
            asm volatile("s_waitcnt vmcnt(0)" ::: "memory");
        }
        asm volatile("s_barrier" ::: "memory");                 // PRE: tile kt visible to all
        bf16x8 af[4], bfr[6];
#pragma unroll
        for (int a = 0; a < 4; ++a)
            af[a] = *reinterpret_cast<const bf16x8*>(
                &a_l[bcur][(wr * 64 + a * 16 + c) * 32 + (g ^ rsl) * 8]);
#pragma unroll
        for (int b = 0; b < 6; ++b)
            bfr[b] = *reinterpret_cast<const bf16x8*>(
                &b_l[bcur][(wc * 96 + b * 16 + c) * 32 + (g ^ rsl) * 8]);
#pragma unroll
        for (int a = 0; a < 4; ++a)
#pragma unroll
            for (int b = 0; b < 6; ++b)
                acc[a][b] = __builtin_amdgcn_mfma_f32_16x16x32_bf16(af[a], bfr[b], acc[a][b], 0, 0, 0);
        if (kt + 1 < nsteps)
            asm volatile("s_barrier" ::: "memory");             // POST: buf safe to overwrite
    }
#undef K5_STAGE

    unsigned short* pp = part + ((size_t)ks * BL + bl0) * E_ + e0;
#pragma unroll
    for (int a = 0; a < 4; ++a)
#pragma unroll
        for (int b = 0; b < 6; ++b)
#pragma unroll
            for (int i = 0; i < 4; ++i)
                pp[(size_t)(wr * 64 + a * 16 + g * 4 + i) * E_ + wc * 96 + b * 16 + c] =
                    f2bf(acc[a][b][i]);
}

// ---------------------------------------------------------------- k6: out = sum of 6 bf16 partials
__global__ __launch_bounds__(256) void k6_red(const unsigned short* __restrict__ part,
                                              float* __restrict__ out) {
    const size_t base = ((size_t)blockIdx.x * 256 + threadIdx.x) * 8;
    float s[8] = {};
#pragma unroll
    for (int ks = 0; ks < 6; ++ks) {
        uint4 v = *reinterpret_cast<const uint4*>(part + (size_t)ks * (BL * E_) + base);
        const unsigned u[4] = {v.x, v.y, v.z, v.w};
#pragma unroll
        for (int j = 0; j < 4; ++j) {
            s[2 * j]     += bf2f(u[j] & 0xffffu);
            s[2 * j + 1] += bf2f(u[j] >> 16);
        }
    }
    *reinterpret_cast<float4*>(out + base)     = make_float4(s[0], s[1], s[2], s[3]);
    *reinterpret_cast<float4*>(out + base + 4) = make_float4(s[4], s[5], s[6], s[7]);
}

// ----------------------------------------------------------------
extern "C" void kernel_launch(void* const* d_in, const int* in_sizes, int n_in,
                              void* d_out, int out_size, void* d_ws, size_t ws_size,
                              hipStream_t stream) {
    const float* topk  = (const float*)d_in[0];
    const float* ts    = (const float*)d_in[1];
    const float* probs = (const float*)d_in[2];
    const float* qp    = (const float*)d_in[3];
    const float* kp    = (const float*)d_in[4];
    const float* vp    = (const float*)d_in[5];
    const float* ow    = (const float*)d_in[6];
    const float* ob    = (const float*)d_in[7];
    float* out = (float*)d_out;

    char* wp = (char*)d_ws;
    float* kk            = (float*)wp;           wp += 524288;
    float* vv            = (float*)wp;           wp += 524288;
    float* ab            = (float*)wp;           wp += 16384;
    unsigned short* tsb  = (unsigned short*)wp;  wp += 2097152;
    unsigned short* A2t  = (unsigned short*)wp;  wp += 2097152;
    unsigned short* VWt  = (unsigned short*)wp;  wp += (size_t)E_ * LDP * 2;   // 6,389,760
    unsigned short* P    = (unsigned short*)wp;  wp += (size_t)BL * LDP * 2;   // 34,078,720
    unsigned short* part = (unsigned short*)wp;  // 6 * 4096*768*2 = 37,748,736

    k1_kv <<<dim3(32, 16), 256, 0, stream>>>(topk, kp, vp, kk, vv);
    k0_cvt<<<1152,         256, 0, stream>>>(ts, probs, ob, tsb, P, VWt);
    k23   <<<dim3(32, 8),  768, 0, stream>>>(qp, kk, ow, vv, A2t, ab, VWt);
    k4_att<<<dim3(32, 16), 256, 0, stream>>>(A2t, tsb, ab, probs, P);
    k5_out<<<768,          256, 0, stream>>>(P, VWt, part);
    k6_red<<<1536,         256, 0, stream>>>(part, out);
}

// Round 15
// 109.320 us; speedup vs baseline: 1.2827x; 1.0412x over previous
//
#include <hip/hip_runtime.h>
#include <hip/hip_bf16.h>

#define C_   32
#define K_   16
#define DLLM 768
#define DM   256
#define H_   8
#define DK   32
#define G_   256
#define BL   4096
#define NN   4096
#define E_   768
#define LDP  4160          // P / VWt row stride: 4096 + 32 bias-fold + 32 zero pad
#define TEMPF 0.17677669529663687f
#define SCL2  0.2550348647f   // TEMP * log2(e)

typedef __attribute__((ext_vector_type(8))) short bf16x8;
typedef __attribute__((ext_vector_type(4))) float f32x4;
typedef unsigned int u32;

__device__ __forceinline__ unsigned short f2bf(float f) {
    unsigned int u = __float_as_uint(f);
    unsigned int r = (u + 0x7fffu + ((u >> 16) & 1u)) >> 16;
    return (unsigned short)r;
}
__device__ __forceinline__ float bf2f(unsigned int u) {
    return __uint_as_float(u << 16);
}

// async global -> LDS, 16 bytes per lane (wave-uniform LDS base + lane*16)
__device__ __forceinline__ void gl16(const void* g, void* l) {
    __builtin_amdgcn_global_load_lds(
        (const __attribute__((address_space(1))) u32*)g,
        (__attribute__((address_space(3))) u32*)l, 16, 0, 0);
}

// ---------------------------------------------------------------- K1: kk/vv projections
// Coalesced wave-per-row; ALL 4 g-rows' loads hoisted upfront (24 float4 in flight);
// reduce-scatter butterfly (32 shfl+add vs 384): lane even holds (mat=lane>>5,
// k=bit4*8+bit3*4+bit2*2+bit1) after 6 stages.
__global__ __launch_bounds__(256, 2) void k1_kv(const float* __restrict__ topk,
                                                const float* __restrict__ kp,
                                                const float* __restrict__ vp,
                                                float* __restrict__ kk,
                                                float* __restrict__ vv) {
    const int c  = blockIdx.x;          // 0..31
    const int gq = blockIdx.y;          // 0..15
    const int t = threadIdx.x;
    const int lane = t & 63, w = t >> 6;

    __shared__ float t_l[K_][DLLM];     // 48 KB
    {
        const float4* src = reinterpret_cast<const float4*>(topk + (size_t)c * K_ * DLLM);
        float4* dst = reinterpret_cast<float4*>(&t_l[0][0]);
#pragma unroll
        for (int i = 0; i < 12; ++i)
            dst[t + i * 256] = src[t + i * 256];
    }

    const int g0 = gq * 16 + w * 4;
    const int dbase = lane * 4;

    // hoist ALL loads: 4 g-rows x 3 chunks x (kp,vp) = 24 float4 + 8 uniform biases
    float4 ck[4][3], cv[4][3];
    float bk[4], bv[4];
#pragma unroll
    for (int gi = 0; gi < 4; ++gi) {
        const float* kpr = kp + (size_t)(c * G_ + g0 + gi) * (DLLM + 1);
        const float* vpr = vp + (size_t)(c * G_ + g0 + gi) * (DLLM + 1);
#pragma unroll
        for (int r = 0; r < 3; ++r) {
            ck[gi][r] = *reinterpret_cast<const float4*>(kpr + r * 256 + dbase);
            cv[gi][r] = *reinterpret_cast<const float4*>(vpr + r * 256 + dbase);
        }
        bk[gi] = kpr[DLLM];
        bv[gi] = vpr[DLLM];
    }
    __syncthreads();

#pragma unroll
    for (int gi = 0; gi < 4; ++gi) {
        float acc[32] = {};                        // 0..15 kk, 16..31 vv
#pragma unroll
        for (int r = 0; r < 3; ++r) {
            const int d = r * 256 + dbase;
#pragma unroll
            for (int k = 0; k < K_; ++k) {
                float4 t4 = *reinterpret_cast<const float4*>(&t_l[k][d]);
                acc[k]      += ck[gi][r].x * t4.x + ck[gi][r].y * t4.y
                             + ck[gi][r].z * t4.z + ck[gi][r].w * t4.w;
                acc[k + 16] += cv[gi][r].x * t4.x + cv[gi][r].y * t4.y
                             + cv[gi][r].z * t4.z + cv[gi][r].w * t4.w;
            }
        }
        // reduce-scatter: 32 -> 1 accumulator, outputs distributed over lanes
#pragma unroll
        for (int j = 0; j < 16; ++j) {
            float send = (lane & 32) ? acc[j] : acc[j + 16];
            float r = __shfl_xor(send, 32);
            acc[j] = ((lane & 32) ? acc[j + 16] : acc[j]) + r;
        }
#pragma unroll
        for (int j = 0; j < 8; ++j) {
            float send = (lane & 16) ? acc[j] : acc[j + 8];
            float r = __shfl_xor(send, 16);
            acc[j] = ((lane & 16) ? acc[j + 8] : acc[j]) + r;
        }
#pragma unroll
        for (int j = 0; j < 4; ++j) {
            float send = (lane & 8) ? acc[j] : acc[j + 4];
            float r = __shfl_xor(send, 8);
            acc[j] = ((lane & 8) ? acc[j + 4] : acc[j]) + r;
        }
#pragma unroll
        for (int j = 0; j < 2; ++j) {
            float send = (lane & 4) ? acc[j] : acc[j + 2];
            float r = __shfl_xor(send, 4);
            acc[j] = ((lane & 4) ? acc[j + 2] : acc[j]) + r;
        }
        {
            float send = (lane & 2) ? acc[0] : acc[1];
            float r = __shfl_xor(send, 2);
            acc[0] = ((lane & 2) ? acc[1] : acc[0]) + r;
        }
        acc[0] += __shfl_xor(acc[0], 1);

        if ((lane & 1) == 0) {
            const int mat = lane >> 5;
            const int k = ((lane >> 4) & 1) * 8 + ((lane >> 3) & 1) * 4
                        + ((lane >> 2) & 1) * 2 + ((lane >> 1) & 1);
            float val = acc[0] + (mat ? bv[gi] : bk[gi]);
            float* dst = mat ? vv : kk;
            dst[(size_t)(c * K_ + k) * G_ + (g0 + gi)] = val;
        }
    }
}

// ---------------------------------------------------------------- k0: ts->bf16 + bias-fold + zero-pad columns of P and VWt
__global__ __launch_bounds__(256) void k0_cvt(const float* __restrict__ ts,
                                              const float* __restrict__ probs,
                                              const float* __restrict__ outb,
                                              unsigned short* __restrict__ tsb,
                                              unsigned short* __restrict__ P,
                                              unsigned short* __restrict__ VWt) {
    const int bid = blockIdx.x, t = threadIdx.x;
    if (bid < 1024) {                              // ts (4096x256) -> bf16
        const int idx = bid * 1024 + t * 4;
        float4 v = *reinterpret_cast<const float4*>(ts + idx);
        uint2 o;
        o.x = f2bf(v.x) | ((unsigned)f2bf(v.y) << 16);
        o.y = f2bf(v.z) | ((unsigned)f2bf(v.w) << 16);
        *reinterpret_cast<uint2*>(tsb + idx) = o;
    } else if (bid < 1056) {                       // P[:,4096+c]=probs, P[:,4128..4159]=0
        const int b2 = bid - 1024;
        const int row = b2 * 128 + (t >> 1);
        const int ch = (t & 1) * 16;
        unsigned short o[16];
#pragma unroll
        for (int j = 0; j < 16; ++j) o[j] = f2bf(probs[row * 32 + ch + j]);
        uint4 u0, u1;
        u0.x = o[0] | (o[1] << 16);  u0.y = o[2] | (o[3] << 16);
        u0.z = o[4] | (o[5] << 16);  u0.w = o[6] | (o[7] << 16);
        u1.x = o[8] | (o[9] << 16);  u1.y = o[10] | (o[11] << 16);
        u1.z = o[12] | (o[13] << 16); u1.w = o[14] | (o[15] << 16);
        unsigned short* dst = P + (size_t)row * LDP + 4096 + ch;
        *reinterpret_cast<uint4*>(dst) = u0;
        *reinterpret_cast<uint4*>(dst + 8) = u1;
        uint4 z = {0u, 0u, 0u, 0u};
        unsigned short* pz = P + (size_t)row * LDP + 4128 + ch;
        *reinterpret_cast<uint4*>(pz) = z;
        *reinterpret_cast<uint4*>(pz + 8) = z;
    } else {                                       // VWt[e][4096+c]=outb[c][e]; pad=0
        const int idx = (bid - 1056) * 256 + t;    // 768*32 = 24576
        const int e = idx >> 5, cc = idx & 31;
        VWt[(size_t)e * LDP + 4096 + cc] = f2bf(outb[cc * E_ + e]);
        VWt[(size_t)e * LDP + 4128 + cc] = 0;
    }
}

// ---------------------------------------------------------------- K23: (merged) A2t + VWt builders
__global__ __launch_bounds__(768) void k23(const float* __restrict__ qp,
                                           const float* __restrict__ kk,
                                           const float* __restrict__ ow,
                                           const float* __restrict__ vv,
                                           unsigned short* __restrict__ A2t,
                                           float* __restrict__ abias,
                                           unsigned short* __restrict__ VWt) {
    const int c = blockIdx.x, h = blockIdx.y;
    const int t = threadIdx.x;
    __shared__ float kk_l[K_][DK];
    __shared__ float v_l[K_][DK];
    __shared__ float bq_l[DK];
    if (t < 512) {
        int k = t / DK, d = t % DK;
        kk_l[k][d] = kk[(size_t)(c * K_ + k) * G_ + h * DK + d];
        v_l[k][d]  = vv[(size_t)(c * K_ + k) * G_ + h * DK + d];
    }
    if (t < DK)
        bq_l[t] = qp[(size_t)(c * G_ + h * DK + t) * (DM + 1) + DM];
    __syncthreads();
    const int ch = c * H_ + h;
    {   // k3: VWt[e][n]
        const int e = t;
        float acc[K_];
#pragma unroll
        for (int k = 0; k < K_; ++k) acc[k] = 0.f;
        for (int d = 0; d < DK; ++d) {
            float w = ow[((size_t)ch * DK + d) * E_ + e];
#pragma unroll
            for (int k = 0; k < K_; ++k) acc[k] += w * v_l[k][d];
        }
#pragma unroll
        for (int k = 0; k < K_; ++k)
            VWt[(size_t)e * LDP + ch * 16 + k] = f2bf(acc[k]);
    }
    if (t < 256) {  // k2: A2t[n][m] (pre-scaled), abias
        const int m = t;
        float acc[K_];
#pragma unroll
        for (int k = 0; k < K_; ++k) acc[k] = 0.f;
        for (int d = 0; d < DK; ++d) {
            float wq = qp[(size_t)(c * G_ + h * DK + d) * (DM + 1) + m];
#pragma unroll
            for (int k = 0; k < K_; ++k) acc[k] += wq * kk_l[k][d];
        }
#pragma unroll
        for (int k = 0; k < K_; ++k)
            A2t[(size_t)(ch * 16 + k) * DM + m] = f2bf(acc[k] * SCL2);
        if (m < K_) {
            float s = 0.f;
#pragma unroll
            for (int d = 0; d < DK; ++d) s += bq_l[d] * kk_l[m][d];
            abias[ch * 16 + m] = s * SCL2;
        }
    }
}

// ---------------------------------------------------------------- K4: MFMA logits + exp2-softmax + prob scale -> P bf16
// BM(n)=128 x BN(bl)=256, BK=32; 3-buffer depth-2, counted vmcnt BEFORE pre-barrier (round-11 known-good)
__global__ __launch_bounds__(256, 2) void k4_att(const unsigned short* __restrict__ A2t,
                                                 const unsigned short* __restrict__ tsb,
                                                 const float* __restrict__ abias,
                                                 const float* __restrict__ probs,
                                                 unsigned short* __restrict__ P) {
    const int n0  = blockIdx.x * 128;
    const int bl0 = blockIdx.y * 256;
    const int t = threadIdx.x;
    const int lane = t & 63, w = t >> 6;
    const int wr = w >> 1, wc = w & 1;
    const int c = lane & 15, g = lane >> 4;
    const int rsl = (c >> 1) & 3;

    __shared__ unsigned short a_l[3][128 * 32];    // 3 x 8 KB
    __shared__ unsigned short b_l[3][256 * 32];    // 3 x 16 KB
    __shared__ float ab_l[128];
    __shared__ float pb_l[256];

    if (t < 128) ab_l[t] = abias[n0 + t];
    pb_l[t] = probs[(size_t)(bl0 + t) * C_ + (n0 >> 7)];

    const int srow = t >> 2;
    const int sw = ((t & 3) ^ ((t >> 3) & 3)) * 8;

#define K4_STAGE(buf, kt)                                                         \
    {                                                                             \
        const int col_ = (kt) * 32 + sw;                                          \
        _Pragma("unroll")                                                         \
        for (int j = 0; j < 2; ++j)                                               \
            gl16(A2t + (size_t)(n0 + j * 64 + srow) * DM + col_,                  \
                 &a_l[buf][j * 2048 + t * 8]);                                    \
        _Pragma("unroll")                                                         \
        for (int j = 0; j < 4; ++j)                                               \
            gl16(tsb + (size_t)(bl0 + j * 64 + srow) * DM + col_,                 \
                 &b_l[buf][j * 2048 + t * 8]);                                    \
    }

    K4_STAGE(0, 0)
    K4_STAGE(1, 1)
    asm volatile("s_waitcnt lgkmcnt(0)" ::: "memory");   // pb/ab ds_writes published at first barrier

    f32x4 acc[4][8] = {};

#pragma unroll
    for (int kt = 0; kt < 8; ++kt) {
        const int bcur = kt % 3;
        if (kt < 6) {
            K4_STAGE((kt + 2) % 3, kt + 2)
            asm volatile("s_waitcnt vmcnt(12)" ::: "memory");   // tile kt arrived (mine)
        } else if (kt == 6) {
            asm volatile("s_waitcnt vmcnt(6)" ::: "memory");
        } else {
            asm volatile("s_waitcnt vmcnt(0)" ::: "memory");
        }
        asm volatile("s_barrier" ::: "memory");                 // PRE: tile kt visible to all
        bf16x8 af[4], bfr[8];
#pragma unroll
        for (int a = 0; a < 4; ++a)
            af[a] = *reinterpret_cast<const bf16x8*>(
                &a_l[bcur][(wr * 64 + a * 16 + c) * 32 + (g ^ rsl) * 8]);
#pragma unroll
        for (int b = 0; b < 8; ++b)
            bfr[b] = *reinterpret_cast<const bf16x8*>(
                &b_l[bcur][(wc * 128 + b * 16 + c) * 32 + (g ^ rsl) * 8]);
#pragma unroll
        for (int a = 0; a < 4; ++a)
#pragma unroll
            for (int b = 0; b < 8; ++b)
                acc[a][b] = __builtin_amdgcn_mfma_f32_16x16x32_bf16(af[a], bfr[b], acc[a][b], 0, 0, 0);
        if (kt < 7)
            asm volatile("s_barrier" ::: "memory");             // POST: buf[bcur] safe to overwrite
    }
#undef K4_STAGE

#pragma unroll
    for (int a = 0; a < 4; ++a) {
        const int nbase = wr * 64 + a * 16 + g * 4;
#pragma unroll
        for (int b = 0; b < 8; ++b) {
            const int bll = wc * 128 + b * 16 + c;
            float e0 = __builtin_amdgcn_exp2f(acc[a][b][0] + ab_l[nbase + 0]);
            float e1 = __builtin_amdgcn_exp2f(acc[a][b][1] + ab_l[nbase + 1]);
            float e2 = __builtin_amdgcn_exp2f(acc[a][b][2] + ab_l[nbase + 2]);
            float e3 = __builtin_amdgcn_exp2f(acc[a][b][3] + ab_l[nbase + 3]);
            float s = (e0 + e1) + (e2 + e3);
            s += __shfl_xor(s, 16);
            s += __shfl_xor(s, 32);
            const float pv = pb_l[bll] * __builtin_amdgcn_rcpf(s);
            unsigned r0, r1;
            float p0 = e0 * pv, p1 = e1 * pv, p2 = e2 * pv, p3 = e3 * pv;
            asm("v_cvt_pk_bf16_f32 %0, %1, %2" : "=v"(r0) : "v"(p0), "v"(p1));
            asm("v_cvt_pk_bf16_f32 %0, %1, %2" : "=v"(r1) : "v"(p2), "v"(p3));
            uint2 o; o.x = r0; o.y = r1;
            *reinterpret_cast<uint2*>(P + (size_t)(bl0 + bll) * LDP + n0 + nbase) = o;
        }
    }
}

// ---------------------------------------------------------------- K5: part[ks] = P(K-sixth) @ VWt^T  (bf16 partials)
// BM=128, BN=192, BK=32; 2-buffer depth-1 counted vmcnt; split-K=6 -> 768 blocks = 3/CU
__global__ __launch_bounds__(256, 3) void k5_out(const unsigned short* __restrict__ P,
                                                 const unsigned short* __restrict__ VWt,
                                                 unsigned short* __restrict__ part) {
    const int wg = blockIdx.x;                     // 0..767
    const int xcd = wg & 7;
    const int local = wg >> 3;                     // 0..95 = 4 bl x 4 e x 6 ks
    const int bl0 = (xcd * 4 + (local & 3)) * 128;
    const int e0  = ((local >> 2) & 3) * 192;
    const int ks  = local >> 4;                    // 0..5

    const int t = threadIdx.x;
    const int lane = t & 63, w = t >> 6;
    const int wr = w >> 1, wc = w & 1;
    const int c = lane & 15, g = lane >> 4;
    const int rsl = (c >> 1) & 3;

    __shared__ unsigned short a_l[2][128 * 32];    // 2 x 8 KB
    __shared__ unsigned short b_l[2][192 * 32];    // 2 x 12 KB

    const int nstart = ks * 704;                   // 22 steps x 32; last gets 20
    const int nsteps = (ks == 5) ? 20 : 22;

    const int srow = t >> 2;
    const int sw = ((t & 3) ^ ((t >> 3) & 3)) * 8;

#define K5_STAGE(buf, kt)                                                         \
    {                                                                             \
        const int col_ = nstart + (kt) * 32 + sw;                                 \
        _Pragma("unroll")                                                         \
        for (int j = 0; j < 2; ++j)                                               \
            gl16(P + (size_t)(bl0 + j * 64 + srow) * LDP + col_,                  \
                 &a_l[buf][j * 2048 + t * 8]);                                    \
        _Pragma("unroll")                                                         \
        for (int j = 0; j < 3; ++j)                                               \
            gl16(VWt + (size_t)(e0 + j * 64 + srow) * LDP + col_,                 \
                 &b_l[buf][j * 2048 + t * 8]);                                    \
    }

    K5_STAGE(0, 0)

    f32x4 acc[4][6] = {};
    for (int kt = 0; kt < nsteps; ++kt) {
        const int bcur = kt & 1;
        if (kt + 1 < nsteps) {
            K5_STAGE(bcur ^ 1, kt + 1)
            asm volatile("s_waitcnt vmcnt(5)" ::: "memory");    // tile kt arrived (mine)
        } else {
            asm volatile("s_waitcnt vmcnt(0)" ::: "memory");
        }
        asm volatile("s_barrier" ::: "memory");                 // PRE: tile kt visible to all
        bf16x8 af[4], bfr[6];
#pragma unroll
        for (int a = 0; a < 4; ++a)
            af[a] = *reinterpret_cast<const bf16x8*>(
                &a_l[bcur][(wr * 64 + a * 16 + c) * 32 + (g ^ rsl) * 8]);
#pragma unroll
        for (int b = 0; b < 6; ++b)
            bfr[b] = *reinterpret_cast<const bf16x8*>(
                &b_l[bcur][(wc * 96 + b * 16 + c) * 32 + (g ^ rsl) * 8]);
#pragma unroll
        for (int a = 0; a < 4; ++a)
#pragma unroll
            for (int b = 0; b < 6; ++b)
                acc[a][b] = __builtin_amdgcn_mfma_f32_16x16x32_bf16(af[a], bfr[b], acc[a][b], 0, 0, 0);
        if (kt + 1 < nsteps)
            asm volatile("s_barrier" ::: "memory");             // POST: buf safe to overwrite
    }
#undef K5_STAGE

    unsigned short* pp = part + ((size_t)ks * BL + bl0) * E_ + e0;
#pragma unroll
    for (int a = 0; a < 4; ++a)
#pragma unroll
        for (int b = 0; b < 6; ++b)
#pragma unroll
            for (int i = 0; i < 4; ++i)
                pp[(size_t)(wr * 64 + a * 16 + g * 4 + i) * E_ + wc * 96 + b * 16 + c] =
                    f2bf(acc[a][b][i]);
}

// ---------------------------------------------------------------- k6: out = sum of 6 bf16 partials
__global__ __launch_bounds__(256) void k6_red(const unsigned short* __restrict__ part,
                                              float* __restrict__ out) {
    const size_t base = ((size_t)blockIdx.x * 256 + threadIdx.x) * 8;
    float s[8] = {};
#pragma unroll
    for (int ks = 0; ks < 6; ++ks) {
        uint4 v = *reinterpret_cast<const uint4*>(part + (size_t)ks * (BL * E_) + base);
        const unsigned u[4] = {v.x, v.y, v.z, v.w};
#pragma unroll
        for (int j = 0; j < 4; ++j) {
            s[2 * j]     += bf2f(u[j] & 0xffffu);
            s[2 * j + 1] += bf2f(u[j] >> 16);
        }
    }
    *reinterpret_cast<float4*>(out + base)     = make_float4(s[0], s[1], s[2], s[3]);
    *reinterpret_cast<float4*>(out + base + 4) = make_float4(s[4], s[5], s[6], s[7]);
}

// ----------------------------------------------------------------
extern "C" void kernel_launch(void* const* d_in, const int* in_sizes, int n_in,
                              void* d_out, int out_size, void* d_ws, size_t ws_size,
                              hipStream_t stream) {
    const float* topk  = (const float*)d_in[0];
    const float* ts    = (const float*)d_in[1];
    const float* probs = (const float*)d_in[2];
    const float* qp    = (const float*)d_in[3];
    const float* kp    = (const float*)d_in[4];
    const float* vp    = (const float*)d_in[5];
    const float* ow    = (const float*)d_in[6];
    const float* ob    = (const float*)d_in[7];
    float* out = (float*)d_out;

    char* wp = (char*)d_ws;
    float* kk            = (float*)wp;           wp += 524288;
    float* vv            = (float*)wp;           wp += 524288;
    float* ab            = (float*)wp;           wp += 16384;
    unsigned short* tsb  = (unsigned short*)wp;  wp += 2097152;
    unsigned short* A2t  = (unsigned short*)wp;  wp += 2097152;
    unsigned short* VWt  = (unsigned short*)wp;  wp += (size_t)E_ * LDP * 2;   // 6,389,760
    unsigned short* P    = (unsigned short*)wp;  wp += (size_t)BL * LDP * 2;   // 34,078,720
    unsigned short* part = (unsigned short*)wp;  // 6 * 4096*768*2 = 37,748,736

    k1_kv <<<dim3(32, 16), 256, 0, stream>>>(topk, kp, vp, kk, vv);
    k0_cvt<<<1152,         256, 0, stream>>>(ts, probs, ob, tsb, P, VWt);
    k23   <<<dim3(32, 8),  768, 0, stream>>>(qp, kk, ow, vv, A2t, ab, VWt);
    k4_att<<<dim3(32, 16), 256, 0, stream>>>(A2t, tsb, ab, probs, P);
    k5_out<<<768,          256, 0, stream>>>(P, VWt, part);
    k6_red<<<1536,         256, 0, stream>>>(part, out);
}

// Round 16
// 99.210 us; speedup vs baseline: 1.4134x; 1.1019x over previous
//
#include <hip/hip_runtime.h>
#include <hip/hip_bf16.h>

#define C_   32
#define K_   16
#define DLLM 768
#define DM   256
#define H_   8
#define DK   32
#define G_   256
#define BL   4096
#define NN   4096
#define E_   768
#define LDP  4160          // P / VWt row stride: 4096 + 32 bias-fold + 32 zero pad
#define TEMPF 0.17677669529663687f
#define SCL2  0.2550348647f   // TEMP * log2(e)

typedef __attribute__((ext_vector_type(8))) short bf16x8;
typedef __attribute__((ext_vector_type(4))) float f32x4;
typedef unsigned int u32;

__device__ __forceinline__ unsigned short f2bf(float f) {
    unsigned int u = __float_as_uint(f);
    unsigned int r = (u + 0x7fffu + ((u >> 16) & 1u)) >> 16;
    return (unsigned short)r;
}
__device__ __forceinline__ float bf2f(unsigned int u) {
    return __uint_as_float(u << 16);
}

// async global -> LDS, 16 bytes per lane (wave-uniform LDS base + lane*16)
__device__ __forceinline__ void gl16(const void* g, void* l) {
    __builtin_amdgcn_global_load_lds(
        (const __attribute__((address_space(1))) u32*)g,
        (__attribute__((address_space(3))) u32*)l, 16, 0, 0);
}

// ---------------------------------------------------------------- K1: kk/vv via MFMA
// Per block (c, nq, mat): stage topk[c] (16x768) as bf16 in LDS (row stride 776 -> 2-way banks);
// wave w owns 16 g-cols (gtile = nq*64 + w*16); B = kp/vp rows loaded fp32, packed bf16 in-reg;
// 24 x mfma_16x16x32, fp32 accum; bias added at store. kk/vv written fp32 (k23 unchanged).
__global__ __launch_bounds__(256) void k1_kv(const float* __restrict__ topk,
                                             const float* __restrict__ kp,
                                             const float* __restrict__ vp,
                                             float* __restrict__ kk,
                                             float* __restrict__ vv) {
    const int cl  = blockIdx.x;          // cluster 0..31
    const int nq  = blockIdx.y;          // 0..3  (64-col slab)
    const int mat = blockIdx.z;          // 0: kk, 1: vv
    const float* src = mat ? vp : kp;
    float* dst       = mat ? vv : kk;

    const int t = threadIdx.x;
    const int lane = t & 63, w = t >> 6;
    const int c15 = lane & 15, gg = lane >> 4;

    __shared__ unsigned short a_lds[16 * 776];   // ~24.8 KB
#pragma unroll
    for (int i = 0; i < 12; ++i) {               // 16x768 fp32 -> bf16, row stride 776
        const int e = (i * 256 + t) * 4;
        const int r = e / 768, d = e - r * 768;
        float4 v4 = *reinterpret_cast<const float4*>(topk + (size_t)cl * 12288 + e);
        unsigned u0, u1;
        asm("v_cvt_pk_bf16_f32 %0, %1, %2" : "=v"(u0) : "v"(v4.x), "v"(v4.y));
        asm("v_cvt_pk_bf16_f32 %0, %1, %2" : "=v"(u1) : "v"(v4.z), "v"(v4.w));
        uint2 p; p.x = u0; p.y = u1;
        *reinterpret_cast<uint2*>(&a_lds[r * 776 + d]) = p;
    }
    __syncthreads();

    const int gcol = nq * 64 + w * 16 + c15;
    const float* bp = src + (size_t)(cl * G_ + gcol) * (DLLM + 1);
    const float bias = bp[DLLM];

    f32x4 acc = {};
    float4 b0 = *reinterpret_cast<const float4*>(bp + gg * 8);
    float4 b1 = *reinterpret_cast<const float4*>(bp + gg * 8 + 4);
#pragma unroll
    for (int s = 0; s < 24; ++s) {
        float4 n0, n1;
        if (s < 23) {                            // depth-1 prefetch of next K-step
            n0 = *reinterpret_cast<const float4*>(bp + (s + 1) * 32 + gg * 8);
            n1 = *reinterpret_cast<const float4*>(bp + (s + 1) * 32 + gg * 8 + 4);
        }
        union { unsigned u[4]; bf16x8 v; } bb;
        asm("v_cvt_pk_bf16_f32 %0, %1, %2" : "=v"(bb.u[0]) : "v"(b0.x), "v"(b0.y));
        asm("v_cvt_pk_bf16_f32 %0, %1, %2" : "=v"(bb.u[1]) : "v"(b0.z), "v"(b0.w));
        asm("v_cvt_pk_bf16_f32 %0, %1, %2" : "=v"(bb.u[2]) : "v"(b1.x), "v"(b1.y));
        asm("v_cvt_pk_bf16_f32 %0, %1, %2" : "=v"(bb.u[3]) : "v"(b1.z), "v"(b1.w));
        bf16x8 af = *reinterpret_cast<const bf16x8*>(&a_lds[c15 * 776 + s * 32 + gg * 8]);
        acc = __builtin_amdgcn_mfma_f32_16x16x32_bf16(af, bb.v, acc, 0, 0, 0);
        b0 = n0; b1 = n1;
    }

#pragma unroll
    for (int i = 0; i < 4; ++i) {
        const int row = gg * 4 + i;              // topk k-row (A side)
        dst[(size_t)(cl * K_ + row) * G_ + gcol] = acc[i] + bias;
    }
}

// ---------------------------------------------------------------- k0: ts->bf16 + bias-fold + zero-pad columns of P and VWt
__global__ __launch_bounds__(256) void k0_cvt(const float* __restrict__ ts,
                                              const float* __restrict__ probs,
                                              const float* __restrict__ outb,
                                              unsigned short* __restrict__ tsb,
                                              unsigned short* __restrict__ P,
                                              unsigned short* __restrict__ VWt) {
    const int bid = blockIdx.x, t = threadIdx.x;
    if (bid < 1024) {                              // ts (4096x256) -> bf16
        const int idx = bid * 1024 + t * 4;
        float4 v = *reinterpret_cast<const float4*>(ts + idx);
        uint2 o;
        o.x = f2bf(v.x) | ((unsigned)f2bf(v.y) << 16);
        o.y = f2bf(v.z) | ((unsigned)f2bf(v.w) << 16);
        *reinterpret_cast<uint2*>(tsb + idx) = o;
    } else if (bid < 1056) {                       // P[:,4096+c]=probs, P[:,4128..4159]=0
        const int b2 = bid - 1024;
        const int row = b2 * 128 + (t >> 1);
        const int ch = (t & 1) * 16;
        unsigned short o[16];
#pragma unroll
        for (int j = 0; j < 16; ++j) o[j] = f2bf(probs[row * 32 + ch + j]);
        uint4 u0, u1;
        u0.x = o[0] | (o[1] << 16);  u0.y = o[2] | (o[3] << 16);
        u0.z = o[4] | (o[5] << 16);  u0.w = o[6] | (o[7] << 16);
        u1.x = o[8] | (o[9] << 16);  u1.y = o[10] | (o[11] << 16);
        u1.z = o[12] | (o[13] << 16); u1.w = o[14] | (o[15] << 16);
        unsigned short* dst = P + (size_t)row * LDP + 4096 + ch;
        *reinterpret_cast<uint4*>(dst) = u0;
        *reinterpret_cast<uint4*>(dst + 8) = u1;
        uint4 z = {0u, 0u, 0u, 0u};
        unsigned short* pz = P + (size_t)row * LDP + 4128 + ch;
        *reinterpret_cast<uint4*>(pz) = z;
        *reinterpret_cast<uint4*>(pz + 8) = z;
    } else {                                       // VWt[e][4096+c]=outb[c][e]; pad=0
        const int idx = (bid - 1056) * 256 + t;    // 768*32 = 24576
        const int e = idx >> 5, cc = idx & 31;
        VWt[(size_t)e * LDP + 4096 + cc] = f2bf(outb[cc * E_ + e]);
        VWt[(size_t)e * LDP + 4128 + cc] = 0;
    }
}

// ---------------------------------------------------------------- K23: (merged) A2t + VWt builders
__global__ __launch_bounds__(768) void k23(const float* __restrict__ qp,
                                           const float* __restrict__ kk,
                                           const float* __restrict__ ow,
                                           const float* __restrict__ vv,
                                           unsigned short* __restrict__ A2t,
                                           float* __restrict__ abias,
                                           unsigned short* __restrict__ VWt) {
    const int c = blockIdx.x, h = blockIdx.y;
    const int t = threadIdx.x;
    __shared__ float kk_l[K_][DK];
    __shared__ float v_l[K_][DK];
    __shared__ float bq_l[DK];
    if (t < 512) {
        int k = t / DK, d = t % DK;
        kk_l[k][d] = kk[(size_t)(c * K_ + k) * G_ + h * DK + d];
        v_l[k][d]  = vv[(size_t)(c * K_ + k) * G_ + h * DK + d];
    }
    if (t < DK)
        bq_l[t] = qp[(size_t)(c * G_ + h * DK + t) * (DM + 1) + DM];
    __syncthreads();
    const int ch = c * H_ + h;
    {   // k3: VWt[e][n]
        const int e = t;
        float acc[K_];
#pragma unroll
        for (int k = 0; k < K_; ++k) acc[k] = 0.f;
        for (int d = 0; d < DK; ++d) {
            float w = ow[((size_t)ch * DK + d) * E_ + e];
#pragma unroll
            for (int k = 0; k < K_; ++k) acc[k] += w * v_l[k][d];
        }
#pragma unroll
        for (int k = 0; k < K_; ++k)
            VWt[(size_t)e * LDP + ch * 16 + k] = f2bf(acc[k]);
    }
    if (t < 256) {  // k2: A2t[n][m] (pre-scaled), abias
        const int m = t;
        float acc[K_];
#pragma unroll
        for (int k = 0; k < K_; ++k) acc[k] = 0.f;
        for (int d = 0; d < DK; ++d) {
            float wq = qp[(size_t)(c * G_ + h * DK + d) * (DM + 1) + m];
#pragma unroll
            for (int k = 0; k < K_; ++k) acc[k] += wq * kk_l[k][d];
        }
#pragma unroll
        for (int k = 0; k < K_; ++k)
            A2t[(size_t)(ch * 16 + k) * DM + m] = f2bf(acc[k] * SCL2);
        if (m < K_) {
            float s = 0.f;
#pragma unroll
            for (int d = 0; d < DK; ++d) s += bq_l[d] * kk_l[m][d];
            abias[ch * 16 + m] = s * SCL2;
        }
    }
}

// ---------------------------------------------------------------- K4: MFMA logits + exp2-softmax + prob scale -> P bf16
// BM(n)=128 x BN(bl)=256, BK=32; 3-buffer depth-2, counted vmcnt BEFORE pre-barrier (round-11 known-good)
__global__ __launch_bounds__(256, 2) void k4_att(const unsigned short* __restrict__ A2t,
                                                 const unsigned short* __restrict__ tsb,
                                                 const float* __restrict__ abias,
                                                 const float* __restrict__ probs,
                                                 unsigned short* __restrict__ P) {
    const int n0  = blockIdx.x * 128;
    const int bl0 = blockIdx.y * 256;
    const int t = threadIdx.x;
    const int lane = t & 63, w = t >> 6;
    const int wr = w >> 1, wc = w & 1;
    const int c = lane & 15, g = lane >> 4;
    const int rsl = (c >> 1) & 3;

    __shared__ unsigned short a_l[3][128 * 32];    // 3 x 8 KB
    __shared__ unsigned short b_l[3][256 * 32];    // 3 x 16 KB
    __shared__ float ab_l[128];
    __shared__ float pb_l[256];

    if (t < 128) ab_l[t] = abias[n0 + t];
    pb_l[t] = probs[(size_t)(bl0 + t) * C_ + (n0 >> 7)];

    const int srow = t >> 2;
    const int sw = ((t & 3) ^ ((t >> 3) & 3)) * 8;

#define K4_STAGE(buf, kt)                                                         \
    {                                                                             \
        const int col_ = (kt) * 32 + sw;                                          \
        _Pragma("unroll")                                                         \
        for (int j = 0; j < 2; ++j)                                               \
            gl16(A2t + (size_t)(n0 + j * 64 + srow) * DM + col_,                  \
                 &a_l[buf][j * 2048 + t * 8]);                                    \
        _Pragma("unroll")                                                         \
        for (int j = 0; j < 4; ++j)                                               \
            gl16(tsb + (size_t)(bl0 + j * 64 + srow) * DM + col_,                 \
                 &b_l[buf][j * 2048 + t * 8]);                                    \
    }

    K4_STAGE(0, 0)
    K4_STAGE(1, 1)
    asm volatile("s_waitcnt lgkmcnt(0)" ::: "memory");   // pb/ab ds_writes published at first barrier

    f32x4 acc[4][8] = {};

#pragma unroll
    for (int kt = 0; kt < 8; ++kt) {
        const int bcur = kt % 3;
        if (kt < 6) {
            K4_STAGE((kt + 2) % 3, kt + 2)
            asm volatile("s_waitcnt vmcnt(12)" ::: "memory");   // tile kt arrived (mine)
        } else if (kt == 6) {
            asm volatile("s_waitcnt vmcnt(6)" ::: "memory");
        } else {
            asm volatile("s_waitcnt vmcnt(0)" ::: "memory");
        }
        asm volatile("s_barrier" ::: "memory");                 // PRE: tile kt visible to all
        bf16x8 af[4], bfr[8];
#pragma unroll
        for (int a = 0; a < 4; ++a)
            af[a] = *reinterpret_cast<const bf16x8*>(
                &a_l[bcur][(wr * 64 + a * 16 + c) * 32 + (g ^ rsl) * 8]);
#pragma unroll
        for (int b = 0; b < 8; ++b)
            bfr[b] = *reinterpret_cast<const bf16x8*>(
                &b_l[bcur][(wc * 128 + b * 16 + c) * 32 + (g ^ rsl) * 8]);
#pragma unroll
        for (int a = 0; a < 4; ++a)
#pragma unroll
            for (int b = 0; b < 8; ++b)
                acc[a][b] = __builtin_amdgcn_mfma_f32_16x16x32_bf16(af[a], bfr[b], acc[a][b], 0, 0, 0);
        if (kt < 7)
            asm volatile("s_barrier" ::: "memory");             // POST: buf[bcur] safe to overwrite
    }
#undef K4_STAGE

#pragma unroll
    for (int a = 0; a < 4; ++a) {
        const int nbase = wr * 64 + a * 16 + g * 4;
#pragma unroll
        for (int b = 0; b < 8; ++b) {
            const int bll = wc * 128 + b * 16 + c;
            float e0 = __builtin_amdgcn_exp2f(acc[a][b][0] + ab_l[nbase + 0]);
            float e1 = __builtin_amdgcn_exp2f(acc[a][b][1] + ab_l[nbase + 1]);
            float e2 = __builtin_amdgcn_exp2f(acc[a][b][2] + ab_l[nbase + 2]);
            float e3 = __builtin_amdgcn_exp2f(acc[a][b][3] + ab_l[nbase + 3]);
            float s = (e0 + e1) + (e2 + e3);
            s += __shfl_xor(s, 16);
            s += __shfl_xor(s, 32);
            const float pv = pb_l[bll] * __builtin_amdgcn_rcpf(s);
            unsigned r0, r1;
            float p0 = e0 * pv, p1 = e1 * pv, p2 = e2 * pv, p3 = e3 * pv;
            asm("v_cvt_pk_bf16_f32 %0, %1, %2" : "=v"(r0) : "v"(p0), "v"(p1));
            asm("v_cvt_pk_bf16_f32 %0, %1, %2" : "=v"(r1) : "v"(p2), "v"(p3));
            uint2 o; o.x = r0; o.y = r1;
            *reinterpret_cast<uint2*>(P + (size_t)(bl0 + bll) * LDP + n0 + nbase) = o;
        }
    }
}

// ---------------------------------------------------------------- K5: part[ks] = P(K-sixth) @ VWt^T  (bf16 partials)
// BM=128, BN=192, BK=32; 2-buffer depth-1 counted vmcnt; split-K=6 -> 768 blocks = 3/CU
__global__ __launch_bounds__(256, 3) void k5_out(const unsigned short* __restrict__ P,
                                                 const unsigned short* __restrict__ VWt,
                                                 unsigned short* __restrict__ part) {
    const int wg = blockIdx.x;                     // 0..767
    const int xcd = wg & 7;
    const int local = wg >> 3;                     // 0..95 = 4 bl x 4 e x 6 ks
    const int bl0 = (xcd * 4 + (local & 3)) * 128;
    const int e0  = ((local >> 2) & 3) * 192;
    const int ks  = local >> 4;                    // 0..5

    const int t = threadIdx.x;
    const int lane = t & 63, w = t >> 6;
    const int wr = w >> 1, wc = w & 1;
    const int c = lane & 15, g = lane >> 4;
    const int rsl = (c >> 1) & 3;

    __shared__ unsigned short a_l[2][128 * 32];    // 2 x 8 KB
    __shared__ unsigned short b_l[2][192 * 32];    // 2 x 12 KB

    const int nstart = ks * 704;                   // 22 steps x 32; last gets 20
    const int nsteps = (ks == 5) ? 20 : 22;

    const int srow = t >> 2;
    const int sw = ((t & 3) ^ ((t >> 3) & 3)) * 8;

#define K5_STAGE(buf, kt)                                                         \
    {                                                                             \
        const int col_ = nstart + (kt) * 32 + sw;                                 \
        _Pragma("unroll")                                                         \
        for (int j = 0; j < 2; ++j)                                               \
            gl16(P + (size_t)(bl0 + j * 64 + srow) * LDP + col_,                  \
                 &a_l[buf][j * 2048 + t * 8]);                                    \
        _Pragma("unroll")                                                         \
        for (int j = 0; j < 3; ++j)                                               \
            gl16(VWt + (size_t)(e0 + j * 64 + srow) * LDP + col_,                 \
                 &b_l[buf][j * 2048 + t * 8]);                                    \
    }

    K5_STAGE(0, 0)

    f32x4 acc[4][6] = {};
    for (int kt = 0; kt < nsteps; ++kt) {
        const int bcur = kt & 1;
        if (kt + 1 < nsteps) {
            K5_STAGE(bcur ^ 1, kt + 1)
            asm volatile("s_waitcnt vmcnt(5)" ::: "memory");    // tile kt arrived (mine)
        } else {
            asm volatile("s_waitcnt vmcnt(0)" ::: "memory");
        }
        asm volatile("s_barrier" ::: "memory");                 // PRE: tile kt visible to all
        bf16x8 af[4], bfr[6];
#pragma unroll
        for (int a = 0; a < 4; ++a)
            af[a] = *reinterpret_cast<const bf16x8*>(
                &a_l[bcur][(wr * 64 + a * 16 + c) * 32 + (g ^ rsl) * 8]);
#pragma unroll
        for (int b = 0; b < 6; ++b)
            bfr[b] = *reinterpret_cast<const bf16x8*>(
                &b_l[bcur][(wc * 96 + b * 16 + c) * 32 + (g ^ rsl) * 8]);
#pragma unroll
        for (int a = 0; a < 4; ++a)
#pragma unroll
            for (int b = 0; b < 6; ++b)
                acc[a][b] = __builtin_amdgcn_mfma_f32_16x16x32_bf16(af[a], bfr[b], acc[a][b], 0, 0, 0);
        if (kt + 1 < nsteps)
            asm volatile("s_barrier" ::: "memory");             // POST: buf safe to overwrite
    }
#undef K5_STAGE

    unsigned short* pp = part + ((size_t)ks * BL + bl0) * E_ + e0;
#pragma unroll
    for (int a = 0; a < 4; ++a)
#pragma unroll
        for (int b = 0; b < 6; ++b)
#pragma unroll
            for (int i = 0; i < 4; ++i)
                pp[(size_t)(wr * 64 + a * 16 + g * 4 + i) * E_ + wc * 96 + b * 16 + c] =
                    f2bf(acc[a][b][i]);
}

// ---------------------------------------------------------------- k6: out = sum of 6 bf16 partials
__global__ __launch_bounds__(256) void k6_red(const unsigned short* __restrict__ part,
                                              float* __restrict__ out) {
    const size_t base = ((size_t)blockIdx.x * 256 + threadIdx.x) * 8;
    float s[8] = {};
#pragma unroll
    for (int ks = 0; ks < 6; ++ks) {
        uint4 v = *reinterpret_cast<const uint4*>(part + (size_t)ks * (BL * E_) + base);
        const unsigned u[4] = {v.x, v.y, v.z, v.w};
#pragma unroll
        for (int j = 0; j < 4; ++j) {
            s[2 * j]     += bf2f(u[j] & 0xffffu);
            s[2 * j + 1] += bf2f(u[j] >> 16);
        }
    }
    *reinterpret_cast<float4*>(out + base)     = make_float4(s[0], s[1], s[2], s[3]);
    *reinterpret_cast<float4*>(out + base + 4) = make_float4(s[4], s[5], s[6], s[7]);
}

// ----------------------------------------------------------------
extern "C" void kernel_launch(void* const* d_in, const int* in_sizes, int n_in,
                              void* d_out, int out_size, void* d_ws, size_t ws_size,
                              hipStream_t stream) {
    const float* topk  = (const float*)d_in[0];
    const float* ts    = (const float*)d_in[1];
    const float* probs = (const float*)d_in[2];
    const float* qp    = (const float*)d_in[3];
    const float* kp    = (const float*)d_in[4];
    const float* vp    = (const float*)d_in[5];
    const float* ow    = (const float*)d_in[6];
    const float* ob    = (const float*)d_in[7];
    float* out = (float*)d_out;

    char* wp = (char*)d_ws;
    float* kk            = (float*)wp;           wp += 524288;
    float* vv            = (float*)wp;           wp += 524288;
    float* ab            = (float*)wp;           wp += 16384;
    unsigned short* tsb  = (unsigned short*)wp;  wp += 2097152;
    unsigned short* A2t  = (unsigned short*)wp;  wp += 2097152;
    unsigned short* VWt  = (unsigned short*)wp;  wp += (size_t)E_ * LDP * 2;   // 6,389,760
    unsigned short* P    = (unsigned short*)wp;  wp += (size_t)BL * LDP * 2;   // 34,078,720
    unsigned short* part = (unsigned short*)wp;  // 6 * 4096*768*2 = 37,748,736

    k1_kv <<<dim3(32, 4, 2), 256, 0, stream>>>(topk, kp, vp, kk, vv);
    k0_cvt<<<1152,           256, 0, stream>>>(ts, probs, ob, tsb, P, VWt);
    k23   <<<dim3(32, 8),    768, 0, stream>>>(qp, kk, ow, vv, A2t, ab, VWt);
    k4_att<<<dim3(32, 16),   256, 0, stream>>>(A2t, tsb, ab, probs, P);
    k5_out<<<768,            256, 0, stream>>>(P, VWt, part);
    k6_red<<<1536,           256, 0, stream>>>(part, out);
}

// Round 17
// 95.075 us; speedup vs baseline: 1.4749x; 1.0435x over previous
//
#include <hip/hip_runtime.h>
#include <hip/hip_bf16.h>

#define C_   32
#define K_   16
#define DLLM 768
#define DM   256
#define H_   8
#define DK   32
#define G_   256
#define BL   4096
#define NN   4096
#define E_   768
#define LDP  4160          // P / VWt row stride: 4096 + 32 bias-fold + 32 zero pad
#define TEMPF 0.17677669529663687f
#define SCL2  0.2550348647f   // TEMP * log2(e)

typedef __attribute__((ext_vector_type(8))) short bf16x8;
typedef __attribute__((ext_vector_type(4))) float f32x4;
typedef unsigned int u32;

__device__ __forceinline__ unsigned short f2bf(float f) {
    unsigned int u = __float_as_uint(f);
    unsigned int r = (u + 0x7fffu + ((u >> 16) & 1u)) >> 16;
    return (unsigned short)r;
}
__device__ __forceinline__ float bf2f(unsigned int u) {
    return __uint_as_float(u << 16);
}

// async global -> LDS, 16 bytes per lane (wave-uniform LDS base + lane*16)
__device__ __forceinline__ void gl16(const void* g, void* l) {
    __builtin_amdgcn_global_load_lds(
        (const __attribute__((address_space(1))) u32*)g,
        (__attribute__((address_space(3))) u32*)l, 16, 0, 0);
}

// ---------------------------------------------------------------- K01: merged k1(MFMA kk/vv) + k0(cvt/bias-fold) + probsT
// bid 0..255    : k1 — kk/vv via MFMA (cl = bid&31, nq = (bid>>5)&3, mat = bid>>7)
// bid 256..1279 : ts (4096x256) -> bf16
// bid 1280..1311: P[:,4096+c]=probs bf16, P[:,4128..4159]=0
// bid 1312..1407: VWt[e][4096+c]=outb[c][e], pad=0
// bid 1408..1439: probsT[c][bl] = probs[bl][c] (LDS transpose)
__global__ __launch_bounds__(256) void k01(const float* __restrict__ topk,
                                           const float* __restrict__ kp,
                                           const float* __restrict__ vp,
                                           float* __restrict__ kk,
                                           float* __restrict__ vv,
                                           const float* __restrict__ ts,
                                           const float* __restrict__ probs,
                                           const float* __restrict__ outb,
                                           unsigned short* __restrict__ tsb,
                                           unsigned short* __restrict__ P,
                                           unsigned short* __restrict__ VWt,
                                           float* __restrict__ probsT) {
    const int bid = blockIdx.x, t = threadIdx.x;
    __shared__ unsigned short a_lds[16 * 776];   // k1: bf16 topk tile; probsT: reused as fp32 [128][33]

    if (bid < 256) {                               // ---- k1: kk/vv via MFMA
        const int cl  = bid & 31;
        const int nq  = (bid >> 5) & 3;
        const int mat = bid >> 7;
        const float* src = mat ? vp : kp;
        float* dst       = mat ? vv : kk;

        const int lane = t & 63, w = t >> 6;
        const int c15 = lane & 15, gg = lane >> 4;

#pragma unroll
        for (int i = 0; i < 12; ++i) {             // 16x768 fp32 -> bf16, row stride 776
            const int e = (i * 256 + t) * 4;
            const int r = e / 768, d = e - r * 768;
            float4 v4 = *reinterpret_cast<const float4*>(topk + (size_t)cl * 12288 + e);
            unsigned u0, u1;
            asm("v_cvt_pk_bf16_f32 %0, %1, %2" : "=v"(u0) : "v"(v4.x), "v"(v4.y));
            asm("v_cvt_pk_bf16_f32 %0, %1, %2" : "=v"(u1) : "v"(v4.z), "v"(v4.w));
            uint2 p; p.x = u0; p.y = u1;
            *reinterpret_cast<uint2*>(&a_lds[r * 776 + d]) = p;
        }
        __syncthreads();

        const int gcol = nq * 64 + w * 16 + c15;
        const float* bp = src + (size_t)(cl * G_ + gcol) * (DLLM + 1);
        const float bias = bp[DLLM];

        f32x4 acc = {};
        float4 b0 = *reinterpret_cast<const float4*>(bp + gg * 8);
        float4 b1 = *reinterpret_cast<const float4*>(bp + gg * 8 + 4);
#pragma unroll
        for (int s = 0; s < 24; ++s) {
            float4 n0, n1;
            if (s < 23) {
                n0 = *reinterpret_cast<const float4*>(bp + (s + 1) * 32 + gg * 8);
                n1 = *reinterpret_cast<const float4*>(bp + (s + 1) * 32 + gg * 8 + 4);
            }
            union { unsigned u[4]; bf16x8 v; } bb;
            asm("v_cvt_pk_bf16_f32 %0, %1, %2" : "=v"(bb.u[0]) : "v"(b0.x), "v"(b0.y));
            asm("v_cvt_pk_bf16_f32 %0, %1, %2" : "=v"(bb.u[1]) : "v"(b0.z), "v"(b0.w));
            asm("v_cvt_pk_bf16_f32 %0, %1, %2" : "=v"(bb.u[2]) : "v"(b1.x), "v"(b1.y));
            asm("v_cvt_pk_bf16_f32 %0, %1, %2" : "=v"(bb.u[3]) : "v"(b1.z), "v"(b1.w));
            bf16x8 af = *reinterpret_cast<const bf16x8*>(&a_lds[c15 * 776 + s * 32 + gg * 8]);
            acc = __builtin_amdgcn_mfma_f32_16x16x32_bf16(af, bb.v, acc, 0, 0, 0);
            b0 = n0; b1 = n1;
        }
#pragma unroll
        for (int i = 0; i < 4; ++i) {
            const int row = gg * 4 + i;
            dst[(size_t)(cl * K_ + row) * G_ + gcol] = acc[i] + bias;
        }
    } else if (bid < 1280) {                       // ---- ts -> bf16
        const int idx = (bid - 256) * 1024 + t * 4;
        float4 v = *reinterpret_cast<const float4*>(ts + idx);
        uint2 o;
        o.x = f2bf(v.x) | ((unsigned)f2bf(v.y) << 16);
        o.y = f2bf(v.z) | ((unsigned)f2bf(v.w) << 16);
        *reinterpret_cast<uint2*>(tsb + idx) = o;
    } else if (bid < 1312) {                       // ---- P bias-fold + zero pad
        const int b2 = bid - 1280;
        const int row = b2 * 128 + (t >> 1);
        const int ch = (t & 1) * 16;
        unsigned short o[16];
#pragma unroll
        for (int j = 0; j < 16; ++j) o[j] = f2bf(probs[row * 32 + ch + j]);
        uint4 u0, u1;
        u0.x = o[0] | (o[1] << 16);  u0.y = o[2] | (o[3] << 16);
        u0.z = o[4] | (o[5] << 16);  u0.w = o[6] | (o[7] << 16);
        u1.x = o[8] | (o[9] << 16);  u1.y = o[10] | (o[11] << 16);
        u1.z = o[12] | (o[13] << 16); u1.w = o[14] | (o[15] << 16);
        unsigned short* dst = P + (size_t)row * LDP + 4096 + ch;
        *reinterpret_cast<uint4*>(dst) = u0;
        *reinterpret_cast<uint4*>(dst + 8) = u1;
        uint4 z = {0u, 0u, 0u, 0u};
        unsigned short* pz = P + (size_t)row * LDP + 4128 + ch;
        *reinterpret_cast<uint4*>(pz) = z;
        *reinterpret_cast<uint4*>(pz + 8) = z;
    } else if (bid < 1408) {                       // ---- VWt bias-fold
        const int idx = (bid - 1312) * 256 + t;    // 768*32 = 24576
        const int e = idx >> 5, cc = idx & 31;
        VWt[(size_t)e * LDP + 4096 + cc] = f2bf(outb[cc * E_ + e]);
        VWt[(size_t)e * LDP + 4128 + cc] = 0;
    } else {                                       // ---- probsT transpose (32 blocks x 128 rows)
        float* tl = reinterpret_cast<float*>(a_lds);   // [128][33]
        const int bl0p = (bid - 1408) * 128;
#pragma unroll
        for (int i = 0; i < 16; ++i) {
            const int row = i * 8 + (t >> 5);
            const int cc = t & 31;
            tl[row * 33 + cc] = probs[(size_t)(bl0p + row) * C_ + cc];
        }
        __syncthreads();
#pragma unroll
        for (int j = 0; j < 16; ++j) {
            const int cc = j * 2 + (t >> 7);
            const int bl = t & 127;
            probsT[(size_t)cc * BL + bl0p + bl] = tl[bl * 33 + cc];
        }
    }
}

// ---------------------------------------------------------------- K23: (merged) A2t + VWt builders
__global__ __launch_bounds__(768) void k23(const float* __restrict__ qp,
                                           const float* __restrict__ kk,
                                           const float* __restrict__ ow,
                                           const float* __restrict__ vv,
                                           unsigned short* __restrict__ A2t,
                                           float* __restrict__ abias,
                                           unsigned short* __restrict__ VWt) {
    const int c = blockIdx.x, h = blockIdx.y;
    const int t = threadIdx.x;
    __shared__ float kk_l[K_][DK];
    __shared__ float v_l[K_][DK];
    __shared__ float bq_l[DK];
    if (t < 512) {
        int k = t / DK, d = t % DK;
        kk_l[k][d] = kk[(size_t)(c * K_ + k) * G_ + h * DK + d];
        v_l[k][d]  = vv[(size_t)(c * K_ + k) * G_ + h * DK + d];
    }
    if (t < DK)
        bq_l[t] = qp[(size_t)(c * G_ + h * DK + t) * (DM + 1) + DM];
    __syncthreads();
    const int ch = c * H_ + h;
    {   // k3: VWt[e][n]
        const int e = t;
        float acc[K_];
#pragma unroll
        for (int k = 0; k < K_; ++k) acc[k] = 0.f;
        for (int d = 0; d < DK; ++d) {
            float w = ow[((size_t)ch * DK + d) * E_ + e];
#pragma unroll
            for (int k = 0; k < K_; ++k) acc[k] += w * v_l[k][d];
        }
#pragma unroll
        for (int k = 0; k < K_; ++k)
            VWt[(size_t)e * LDP + ch * 16 + k] = f2bf(acc[k]);
    }
    if (t < 256) {  // k2: A2t[n][m] (pre-scaled), abias
        const int m = t;
        float acc[K_];
#pragma unroll
        for (int k = 0; k < K_; ++k) acc[k] = 0.f;
        for (int d = 0; d < DK; ++d) {
            float wq = qp[(size_t)(c * G_ + h * DK + d) * (DM + 1) + m];
#pragma unroll
            for (int k = 0; k < K_; ++k) acc[k] += wq * kk_l[k][d];
        }
#pragma unroll
        for (int k = 0; k < K_; ++k)
            A2t[(size_t)(ch * 16 + k) * DM + m] = f2bf(acc[k] * SCL2);
        if (m < K_) {
            float s = 0.f;
#pragma unroll
            for (int d = 0; d < DK; ++d) s += bq_l[d] * kk_l[m][d];
            abias[ch * 16 + m] = s * SCL2;
        }
    }
}

// ---------------------------------------------------------------- K4: MFMA logits + exp2-softmax + prob scale -> P bf16
// BM(n)=128 x BN(bl)=128, BK=32; 2-buffer depth-1 counted vmcnt; 1024 blocks = 4/CU
__global__ __launch_bounds__(256, 4) void k4_att(const unsigned short* __restrict__ A2t,
                                                 const unsigned short* __restrict__ tsb,
                                                 const float* __restrict__ abias,
                                                 const float* __restrict__ probsT,
                                                 unsigned short* __restrict__ P) {
    const int n0  = blockIdx.x * 128;
    const int bl0 = blockIdx.y * 128;
    const int t = threadIdx.x;
    const int lane = t & 63, w = t >> 6;
    const int wr = w >> 1, wc = w & 1;
    const int c = lane & 15, g = lane >> 4;
    const int rsl = (c >> 1) & 3;

    __shared__ unsigned short a_l[2][128 * 32];    // 8 KB / buf
    __shared__ unsigned short b_l[2][128 * 32];    // 8 KB / buf
    __shared__ float ab_l[128];
    __shared__ float pb_l[128];

    if (t < 128) ab_l[t] = abias[n0 + t];
    else         pb_l[t - 128] = probsT[(size_t)(n0 >> 7) * BL + bl0 + (t - 128)];

    const int srow = t >> 2;
    const int sw = ((t & 3) ^ ((t >> 3) & 3)) * 8;

#define K4_STAGE(buf, kt)                                                         \
    {                                                                             \
        const int col_ = (kt) * 32 + sw;                                          \
        _Pragma("unroll")                                                         \
        for (int j = 0; j < 2; ++j)                                               \
            gl16(A2t + (size_t)(n0 + j * 64 + srow) * DM + col_,                  \
                 &a_l[buf][j * 2048 + t * 8]);                                    \
        _Pragma("unroll")                                                         \
        for (int j = 0; j < 2; ++j)                                               \
            gl16(tsb + (size_t)(bl0 + j * 64 + srow) * DM + col_,                 \
                 &b_l[buf][j * 2048 + t * 8]);                                    \
    }

    K4_STAGE(0, 0)
    asm volatile("s_waitcnt lgkmcnt(0)" ::: "memory");   // pb/ab ds_writes published at first barrier

    f32x4 acc[4][4] = {};

#pragma unroll
    for (int kt = 0; kt < 8; ++kt) {
        const int bcur = kt & 1;
        if (kt < 7) {
            K4_STAGE(bcur ^ 1, kt + 1)
            asm volatile("s_waitcnt vmcnt(4)" ::: "memory");    // tile kt arrived (mine)
        } else {
            asm volatile("s_waitcnt vmcnt(0)" ::: "memory");
        }
        asm volatile("s_barrier" ::: "memory");                 // PRE: tile kt visible to all
        bf16x8 af[4], bfr[4];
#pragma unroll
        for (int a = 0; a < 4; ++a)
            af[a] = *reinterpret_cast<const bf16x8*>(
                &a_l[bcur][(wr * 64 + a * 16 + c) * 32 + (g ^ rsl) * 8]);
#pragma unroll
        for (int b = 0; b < 4; ++b)
            bfr[b] = *reinterpret_cast<const bf16x8*>(
                &b_l[bcur][(wc * 64 + b * 16 + c) * 32 + (g ^ rsl) * 8]);
#pragma unroll
        for (int a = 0; a < 4; ++a)
#pragma unroll
            for (int b = 0; b < 4; ++b)
                acc[a][b] = __builtin_amdgcn_mfma_f32_16x16x32_bf16(af[a], bfr[b], acc[a][b], 0, 0, 0);
        if (kt < 7)
            asm volatile("s_barrier" ::: "memory");             // POST: buf[bcur] safe to overwrite
    }
#undef K4_STAGE

#pragma unroll
    for (int a = 0; a < 4; ++a) {
        const int nbase = wr * 64 + a * 16 + g * 4;
#pragma unroll
        for (int b = 0; b < 4; ++b) {
            const int bll = wc * 64 + b * 16 + c;
            float e0 = __builtin_amdgcn_exp2f(acc[a][b][0] + ab_l[nbase + 0]);
            float e1 = __builtin_amdgcn_exp2f(acc[a][b][1] + ab_l[nbase + 1]);
            float e2 = __builtin_amdgcn_exp2f(acc[a][b][2] + ab_l[nbase + 2]);
            float e3 = __builtin_amdgcn_exp2f(acc[a][b][3] + ab_l[nbase + 3]);
            float s = (e0 + e1) + (e2 + e3);
            s += __shfl_xor(s, 16);
            s += __shfl_xor(s, 32);
            const float pv = pb_l[bll] * __builtin_amdgcn_rcpf(s);
            unsigned r0, r1;
            float p0 = e0 * pv, p1 = e1 * pv, p2 = e2 * pv, p3 = e3 * pv;
            asm("v_cvt_pk_bf16_f32 %0, %1, %2" : "=v"(r0) : "v"(p0), "v"(p1));
            asm("v_cvt_pk_bf16_f32 %0, %1, %2" : "=v"(r1) : "v"(p2), "v"(p3));
            uint2 o; o.x = r0; o.y = r1;
            *reinterpret_cast<uint2*>(P + (size_t)(bl0 + bll) * LDP + n0 + nbase) = o;
        }
    }
}

// ---------------------------------------------------------------- K5: part[ks] = P(K-sixth) @ VWt^T  (bf16 partials)
// BM=128, BN=192, BK=32; 2-buffer depth-1 counted vmcnt; split-K=6 -> 768 blocks = 3/CU
__global__ __launch_bounds__(256, 3) void k5_out(const unsigned short* __restrict__ P,
                                                 const unsigned short* __restrict__ VWt,
                                                 unsigned short* __restrict__ part) {
    const int wg = blockIdx.x;                     // 0..767
    const int xcd = wg & 7;
    const int local = wg >> 3;                     // 0..95 = 4 bl x 4 e x 6 ks
    const int bl0 = (xcd * 4 + (local & 3)) * 128;
    const int e0  = ((local >> 2) & 3) * 192;
    const int ks  = local >> 4;                    // 0..5

    const int t = threadIdx.x;
    const int lane = t & 63, w = t >> 6;
    const int wr = w >> 1, wc = w & 1;
    const int c = lane & 15, g = lane >> 4;
    const int rsl = (c >> 1) & 3;

    __shared__ unsigned short a_l[2][128 * 32];    // 2 x 8 KB
    __shared__ unsigned short b_l[2][192 * 32];    // 2 x 12 KB

    const int nstart = ks * 704;                   // 22 steps x 32; last gets 20
    const int nsteps = (ks == 5) ? 20 : 22;

    const int srow = t >> 2;
    const int sw = ((t & 3) ^ ((t >> 3) & 3)) * 8;

#define K5_STAGE(buf, kt)                                                         \
    {                                                                             \
        const int col_ = nstart + (kt) * 32 + sw;                                 \
        _Pragma("unroll")                                                         \
        for (int j = 0; j < 2; ++j)                                               \
            gl16(P + (size_t)(bl0 + j * 64 + srow) * LDP + col_,                  \
                 &a_l[buf][j * 2048 + t * 8]);                                    \
        _Pragma("unroll")                                                         \
        for (int j = 0; j < 3; ++j)                                               \
            gl16(VWt + (size_t)(e0 + j * 64 + srow) * LDP + col_,                 \
                 &b_l[buf][j * 2048 + t * 8]);                                    \
    }

    K5_STAGE(0, 0)

    f32x4 acc[4][6] = {};
    for (int kt = 0; kt < nsteps; ++kt) {
        const int bcur = kt & 1;
        if (kt + 1 < nsteps) {
            K5_STAGE(bcur ^ 1, kt + 1)
            asm volatile("s_waitcnt vmcnt(5)" ::: "memory");    // tile kt arrived (mine)
        } else {
            asm volatile("s_waitcnt vmcnt(0)" ::: "memory");
        }
        asm volatile("s_barrier" ::: "memory");                 // PRE: tile kt visible to all
        bf16x8 af[4], bfr[6];
#pragma unroll
        for (int a = 0; a < 4; ++a)
            af[a] = *reinterpret_cast<const bf16x8*>(
                &a_l[bcur][(wr * 64 + a * 16 + c) * 32 + (g ^ rsl) * 8]);
#pragma unroll
        for (int b = 0; b < 6; ++b)
            bfr[b] = *reinterpret_cast<const bf16x8*>(
                &b_l[bcur][(wc * 96 + b * 16 + c) * 32 + (g ^ rsl) * 8]);
#pragma unroll
        for (int a = 0; a < 4; ++a)
#pragma unroll
            for (int b = 0; b < 6; ++b)
                acc[a][b] = __builtin_amdgcn_mfma_f32_16x16x32_bf16(af[a], bfr[b], acc[a][b], 0, 0, 0);
        if (kt + 1 < nsteps)
            asm volatile("s_barrier" ::: "memory");             // POST: buf safe to overwrite
    }
#undef K5_STAGE

    unsigned short* pp = part + ((size_t)ks * BL + bl0) * E_ + e0;
#pragma unroll
    for (int a = 0; a < 4; ++a)
#pragma unroll
        for (int b = 0; b < 6; ++b)
#pragma unroll
            for (int i = 0; i < 4; ++i)
                pp[(size_t)(wr * 64 + a * 16 + g * 4 + i) * E_ + wc * 96 + b * 16 + c] =
                    f2bf(acc[a][b][i]);
}

// ---------------------------------------------------------------- k6: out = sum of 6 bf16 partials
__global__ __launch_bounds__(256) void k6_red(const unsigned short* __restrict__ part,
                                              float* __restrict__ out) {
    const size_t base = ((size_t)blockIdx.x * 256 + threadIdx.x) * 8;
    float s[8] = {};
#pragma unroll
    for (int ks = 0; ks < 6; ++ks) {
        uint4 v = *reinterpret_cast<const uint4*>(part + (size_t)ks * (BL * E_) + base);
        const unsigned u[4] = {v.x, v.y, v.z, v.w};
#pragma unroll
        for (int j = 0; j < 4; ++j) {
            s[2 * j]     += bf2f(u[j] & 0xffffu);
            s[2 * j + 1] += bf2f(u[j] >> 16);
        }
    }
    *reinterpret_cast<float4*>(out + base)     = make_float4(s[0], s[1], s[2], s[3]);
    *reinterpret_cast<float4*>(out + base + 4) = make_float4(s[4], s[5], s[6], s[7]);
}

// ----------------------------------------------------------------
extern "C" void kernel_launch(void* const* d_in, const int* in_sizes, int n_in,
                              void* d_out, int out_size, void* d_ws, size_t ws_size,
                              hipStream_t stream) {
    const float* topk  = (const float*)d_in[0];
    const float* ts    = (const float*)d_in[1];
    const float* probs = (const float*)d_in[2];
    const float* qp    = (const float*)d_in[3];
    const float* kp    = (const float*)d_in[4];
    const float* vp    = (const float*)d_in[5];
    const float* ow    = (const float*)d_in[6];
    const float* ob    = (const float*)d_in[7];
    float* out = (float*)d_out;

    char* wp = (char*)d_ws;
    float* kk            = (float*)wp;           wp += 524288;
    float* vv            = (float*)wp;           wp += 524288;
    float* ab            = (float*)wp;           wp += 16384;
    float* probsT        = (float*)wp;           wp += 524288;
    unsigned short* tsb  = (unsigned short*)wp;  wp += 2097152;
    unsigned short* A2t  = (unsigned short*)wp;  wp += 2097152;
    unsigned short* VWt  = (unsigned short*)wp;  wp += (size_t)E_ * LDP * 2;   // 6,389,760
    unsigned short* P    = (unsigned short*)wp;  wp += (size_t)BL * LDP * 2;   // 34,078,720
    unsigned short* part = (unsigned short*)wp;  // 6 * 4096*768*2 = 37,748,736

    k01   <<<1440,         256, 0, stream>>>(topk, kp, vp, kk, vv,
                                             ts, probs, ob, tsb, P, VWt, probsT);
    k23   <<<dim3(32, 8),  768, 0, stream>>>(qp, kk, ow, vv, A2t, ab, VWt);
    k4_att<<<dim3(32, 32), 256, 0, stream>>>(A2t, tsb, ab, probsT, P);
    k5_out<<<768,          256, 0, stream>>>(P, VWt, part);
    k6_red<<<1536,         256, 0, stream>>>(part, out);
}